// Round 4
// baseline (262.157 us; speedup 1.0000x reference)
//
#include <hip/hip_runtime.h>

// CrossAttentionModel on MI355X (gfx950) — round 4.
//
// Math (softmax row-constant invariance + sum(w)=1):
//   Mt[f][e] = sum_a Wk[f][a] Wq[e][a]   (split-bf16 3-pass, ~f32 accurate)
//   wvec[f]  = Wk bq ; cvec[e] = bv Wo + bo
//   q'[i][f] = sum_e x[i][e] Mt[f][e] + wvec[f]  (3-pass, stored fp16)
//   scores   = q' y^T   (fp16 32x32x16 MFMA)
//   out      = (softmax(scores) y) (Wv Wo) + cvec   (fp16 value path)
//
// R4 vs R3: flash splits operand traffic across pipes — score-A (y) via LDS
// (async-staged), PV-B (y) direct from global (L1/L2-hot, XCD-grouped);
// 256-thread blocks (128 q), grid 512 = 2 blocks/CU; defer-max thr=8;
// qprime n-split for 2 blocks/CU.

#define DEV static __device__ __forceinline__

typedef __attribute__((ext_vector_type(8))) short s8v;        // 8 bf16
typedef __attribute__((ext_vector_type(8))) _Float16 h8v;     // 8 fp16
typedef __attribute__((ext_vector_type(4))) _Float16 h4v;
typedef __attribute__((ext_vector_type(4))) float f4v;
typedef __attribute__((ext_vector_type(16))) float f16f;
typedef __attribute__((ext_vector_type(4))) float float4v;
typedef unsigned short u16;
typedef unsigned int u32;

constexpr int BB = 16;
constexpr int LQ = 1024;
constexpr int LK = 2048;
constexpr int E = 512;
constexpr int F = 256;
constexpr int AD = 512;

DEV u16 f2bf(float x) {
    u32 u = __builtin_bit_cast(u32, x);
    u += 0x7fff + ((u >> 16) & 1);
    return (u16)(u >> 16);
}
DEV float bf2f(u16 h) { return __builtin_bit_cast(float, (u32)h << 16); }

DEV f4v MF(s8v a, s8v b, f4v c) {
    return __builtin_amdgcn_mfma_f32_16x16x32_bf16(a, b, c, 0, 0, 0);
}
DEV f4v MF16(h8v a, h8v b, f4v c) {
    return __builtin_amdgcn_mfma_f32_16x16x32_f16(a, b, c, 0, 0, 0);
}
DEV f16f MF32(h8v a, h8v b, f16f c) {
    return __builtin_amdgcn_mfma_f32_32x32x16_f16(a, b, c, 0, 0, 0);
}

// ---------------------------------------------------------------------------
// wvec[o<256] = sum_a Wk[o][a] bq[a] ; cvec[e] = bo[e] + sum_a bv[a] Wo[a][e]
__global__ __launch_bounds__(256) void kvec2(
    const float* __restrict__ Wk, const float* __restrict__ bq,
    const float* __restrict__ bv, const float* __restrict__ Wo,
    const float* __restrict__ bo, float* __restrict__ wvec,
    float* __restrict__ cvec)
{
    int o = blockIdx.x * 4 + (threadIdx.x >> 6);
    int lane = threadIdx.x & 63;
    float s = 0.f;
    if (o < F) {
        const float* r = Wk + (size_t)o * AD;
#pragma unroll
        for (int i = 0; i < 8; ++i) s += r[lane * 8 + i] * bq[lane * 8 + i];
    } else {
        int e = o - F;
#pragma unroll
        for (int i = 0; i < 8; ++i) {
            int a = lane * 8 + i;
            s += bv[a] * Wo[(size_t)a * E + e];
        }
    }
#pragma unroll
    for (int d = 1; d < 64; d <<= 1) s += __shfl_xor(s, d);
    if (lane == 0) {
        if (o < F) wvec[o] = s;
        else cvec[o - F] = bo[o - F] + s;
    }
}

// ---------------------------------------------------------------------------
// Split-bf16 NT GEMM (weights): C[m][n] = sum_k A[m][k]*B[n][k], K=512.
// MODE 0 (Mt): -> frag-blocked split bf16 (Oh hi, Ol lo) for qprime3 B-frags.
// MODE 2 (Nt): A read transposed; -> frag-blocked fp16 for gemm2c B-frags.
template <int MODE>
__global__ __launch_bounds__(256) void splitnt(
    const float* __restrict__ Ag, const float* __restrict__ Bg,
    u16* __restrict__ Oh, u16* __restrict__ Ol)
{
    __shared__ u16 Ash[64][40], Asl[64][40];
    __shared__ u16 Bsh[256][40], Bsl[256][40];

    const int tid = threadIdx.x;
    const int w = tid >> 6, lane = tid & 63;
    const int g = lane >> 4, qn = lane & 15;
    const int wr = w >> 1, wc = w & 1;
    const int m0 = blockIdx.x * 64, n0 = blockIdx.y * 256;

    f4v acc[2][8];
#pragma unroll
    for (int i = 0; i < 2; ++i)
#pragma unroll
        for (int j = 0; j < 8; ++j) acc[i][j] = (f4v){0.f, 0.f, 0.f, 0.f};

    for (int k0 = 0; k0 < 512; k0 += 32) {
        __syncthreads();
        if (MODE == 0) {
            int r = tid & 63, c = (tid >> 6) * 8;
            const float* s = Ag + (size_t)(m0 + r) * 512 + k0 + c;
            float4v v0 = *(const float4v*)s, v1 = *(const float4v*)(s + 4);
            short hh[8], ll[8];
#pragma unroll
            for (int i = 0; i < 8; ++i) {
                float x = (i < 4) ? v0[i] : v1[i - 4];
                u16 h = f2bf(x);
                hh[i] = (short)h;
                ll[i] = (short)f2bf(x - bf2f(h));
            }
            *(s8v*)&Ash[r][c] = (s8v){hh[0],hh[1],hh[2],hh[3],hh[4],hh[5],hh[6],hh[7]};
            *(s8v*)&Asl[r][c] = (s8v){ll[0],ll[1],ll[2],ll[3],ll[4],ll[5],ll[6],ll[7]};
        } else {
            int k = tid >> 3, mc = (tid & 7) * 8;
            const float* s = Ag + (size_t)(k0 + k) * 512 + m0 + mc;
            float4v v0 = *(const float4v*)s, v1 = *(const float4v*)(s + 4);
#pragma unroll
            for (int i = 0; i < 8; ++i) {
                float x = (i < 4) ? v0[i] : v1[i - 4];
                u16 h = f2bf(x);
                Ash[mc + i][k] = h;
                Asl[mc + i][k] = f2bf(x - bf2f(h));
            }
        }
        {
            const float* s = Bg + (size_t)(n0 + tid) * 512 + k0;
#pragma unroll
            for (int c = 0; c < 32; c += 8) {
                float4v v0 = *(const float4v*)(s + c), v1 = *(const float4v*)(s + c + 4);
                short hh[8], ll[8];
#pragma unroll
                for (int i = 0; i < 8; ++i) {
                    float x = (i < 4) ? v0[i] : v1[i - 4];
                    u16 h = f2bf(x);
                    hh[i] = (short)h;
                    ll[i] = (short)f2bf(x - bf2f(h));
                }
                *(s8v*)&Bsh[tid][c] = (s8v){hh[0],hh[1],hh[2],hh[3],hh[4],hh[5],hh[6],hh[7]};
                *(s8v*)&Bsl[tid][c] = (s8v){ll[0],ll[1],ll[2],ll[3],ll[4],ll[5],ll[6],ll[7]};
            }
        }
        __syncthreads();

        s8v ah[2], al[2], bh[8], bl[8];
#pragma unroll
        for (int mt = 0; mt < 2; ++mt) {
            ah[mt] = *(const s8v*)&Ash[wr * 32 + mt * 16 + qn][g * 8];
            al[mt] = *(const s8v*)&Asl[wr * 32 + mt * 16 + qn][g * 8];
        }
#pragma unroll
        for (int nt = 0; nt < 8; ++nt) {
            bh[nt] = *(const s8v*)&Bsh[wc * 128 + nt * 16 + qn][g * 8];
            bl[nt] = *(const s8v*)&Bsl[wc * 128 + nt * 16 + qn][g * 8];
        }
#pragma unroll
        for (int mt = 0; mt < 2; ++mt)
#pragma unroll
            for (int nt = 0; nt < 8; ++nt) {
                acc[mt][nt] = MF(ah[mt], bh[nt], acc[mt][nt]);
                acc[mt][nt] = MF(ah[mt], bl[nt], acc[mt][nt]);
                acc[mt][nt] = MF(al[mt], bh[nt], acc[mt][nt]);
            }
    }

#pragma unroll
    for (int mt = 0; mt < 2; ++mt)
#pragma unroll
        for (int nt = 0; nt < 8; ++nt)
#pragma unroll
            for (int r = 0; r < 4; ++r) {
                int gm = m0 + wr * 32 + mt * 16 + 4 * g + r;
                int gn = n0 + wc * 128 + nt * 16 + qn;
                float v = acc[mt][nt][r];
                if (MODE == 0) {
                    size_t off = (size_t)((gn >> 5) * 16 + (gm >> 4)) * 512 +
                                 (gm & 15) * 8 + ((gn >> 3) & 3) * 128 + (gn & 7);
                    u16 h = f2bf(v);
                    Oh[off] = h;
                    Ol[off] = f2bf(v - bf2f(h));
                } else {
                    size_t off = (size_t)((gn >> 5) * 32 + (gm >> 4)) * 512 +
                                 (gm & 15) * 8 + ((gn >> 3) & 3) * 128 + (gn & 7);
                    Oh[off] = __builtin_bit_cast(u16, (_Float16)v);
                }
            }
}

// ---------------------------------------------------------------------------
// prep16s: y f32 -> fragment-blocked fp16 arrays for flash4 (unchanged layout).
__global__ __launch_bounds__(256) void prep16s(
    const float* __restrict__ y, _Float16* __restrict__ yA,
    _Float16* __restrict__ yB)
{
    __shared__ float Y[32][260];
    const int tid = threadIdx.x;
    const int b = blockIdx.y, t = blockIdx.x;
    const float* src = y + ((size_t)b * LK + t * 32) * F;
#pragma unroll
    for (int i = 0; i < 8; ++i) {
        int base = i * 1024 + tid * 4;
        int k = base >> 8, f = base & 255;
        *(float4v*)&Y[k][f] = *(const float4v*)(src + base);
    }
    __syncthreads();
    size_t tb = (size_t)(b * 64 + t) * 8192;
#pragma unroll
    for (int i = 0; i < 4; ++i) {
        int c = i * 256 + tid;
        int k = c & 31, hi = (c >> 5) & 1, fs = c >> 6;
        int f0 = fs * 16 + hi * 8;
        float4v v0 = *(const float4v*)&Y[k][f0];
        float4v v1 = *(const float4v*)&Y[k][f0 + 4];
        h8v v;
#pragma unroll
        for (int j = 0; j < 4; ++j) { v[j] = (_Float16)v0[j]; v[4 + j] = (_Float16)v1[j]; }
        *(h8v*)(yA + tb + (size_t)c * 8) = v;
    }
#pragma unroll
    for (int i = 0; i < 4; ++i) {
        int c = i * 256 + tid;
        int fl = c & 31, hi = (c >> 5) & 1, frag = c >> 6;
        int ft = frag >> 1, ks = frag & 1;
        int f = ft * 32 + fl, k0 = ks * 16 + hi * 8;
        h8v v;
#pragma unroll
        for (int j = 0; j < 8; ++j) v[j] = (_Float16)Y[k0 + j][f];
        *(h8v*)(yB + tb + (size_t)c * 8) = v;
    }
}

// ---------------------------------------------------------------------------
// q'[i][f] = sum_e x[i][e] Mt[f][e] + wvec[f] -> fp16.  N-split (grid.y=2).
__global__ __launch_bounds__(256) void qprime3(
    const float* __restrict__ x, const u16* __restrict__ Mthb,
    const u16* __restrict__ Mtlb, const float* __restrict__ wv,
    _Float16* __restrict__ q16)
{
    const int tid = threadIdx.x, w = tid >> 6, lane = tid & 63;
    const int g = lane >> 4, qn = lane & 15;
    const int m0 = blockIdx.x * 64;
    const int nh = blockIdx.y * 8;
    const int arow = m0 + w * 16 + qn;

    f4v acc[8];
#pragma unroll
    for (int n = 0; n < 8; ++n) acc[n] = (f4v){0.f, 0.f, 0.f, 0.f};

    for (int k0 = 0; k0 < 512; k0 += 32) {
        const float* xs = x + (size_t)arow * 512 + k0 + g * 8;
        float4v v0 = *(const float4v*)xs, v1 = *(const float4v*)(xs + 4);
        short hh[8], ll[8];
#pragma unroll
        for (int i = 0; i < 8; ++i) {
            float xv = (i < 4) ? v0[i] : v1[i - 4];
            u16 h = f2bf(xv);
            hh[i] = (short)h;
            ll[i] = (short)f2bf(xv - bf2f(h));
        }
        s8v ah = (s8v){hh[0],hh[1],hh[2],hh[3],hh[4],hh[5],hh[6],hh[7]};
        s8v al = (s8v){ll[0],ll[1],ll[2],ll[3],ll[4],ll[5],ll[6],ll[7]};
        int fb = (k0 >> 5) * 16 + nh;
#pragma unroll
        for (int nt = 0; nt < 8; ++nt) {
            s8v bh = *(const s8v*)(Mthb + (size_t)(fb + nt) * 512 + lane * 8);
            s8v bl = *(const s8v*)(Mtlb + (size_t)(fb + nt) * 512 + lane * 8);
            acc[nt] = MF(ah, bh, acc[nt]);
            acc[nt] = MF(ah, bl, acc[nt]);
            acc[nt] = MF(al, bh, acc[nt]);
        }
    }

#pragma unroll
    for (int nt = 0; nt < 8; ++nt)
#pragma unroll
        for (int r = 0; r < 4; ++r) {
            int row = m0 + w * 16 + 4 * g + r;
            int col = (nh + nt) * 16 + qn;
            q16[(size_t)row * 256 + col] = (_Float16)(acc[nt][r] + wv[col]);
        }
}

// ---------------------------------------------------------------------------
// flash4: grid 512 flat -> (qb 0..7, b, z 0..3), 8 qb-blocks per (b,z) on one
// XCD. 256 threads = 4 waves x 32 q (128 q/block), 512-key chunk, 16 tiles.
// Score-A (y) via LDS async staging; PV-B (y) direct from global frag-blocks;
// defer-max thr=8; per-wave P LDS roundtrip.
__global__ __launch_bounds__(256) void flash4(
    const _Float16* __restrict__ q16, const _Float16* __restrict__ yA,
    const _Float16* __restrict__ yB, _Float16* __restrict__ part,
    float* __restrict__ ml)
{
    __shared__ _Float16 Asb[8192];      // yA tile frags (16KB)
    __shared__ _Float16 Pls[4][1024];   // per-wave P (2KB each)

    const int tid = threadIdx.x;
    const int w = tid >> 6, lane = tid & 63;
    const int q32 = lane & 31, hi = lane >> 5;

    int id = blockIdx.x;
    int xcd = id & 7, slot = id >> 3;       // slot 0..63
    int grp = xcd + 8 * (slot >> 3);        // 0..63 (b,z); fixed xcd per grp
    int qb = slot & 7;
    int b = grp >> 2, z = grp & 3;
    const int qw = qb * 128 + w * 32;

    h8v qf[16];
    {
        const _Float16* qp = q16 + ((size_t)b * LQ + qw + q32) * 256 + hi * 8;
#pragma unroll
        for (int s = 0; s < 16; ++s) qf[s] = *(const h8v*)(qp + s * 16);
    }
    f16f ctx[8];
#pragma unroll
    for (int i = 0; i < 8; ++i) ctx[i] = (f16f){};
    float mrun = -3.0e38f, lrun = 0.f;

    const size_t tbe = (size_t)(b * 64 + z * 16) * 8192;
    h8v sA[4];
    auto LD = [&](int t) {
        const h8v* pa = (const h8v*)(yA + tbe + (size_t)t * 8192);
        sA[0] = pa[tid]; sA[1] = pa[tid + 256];
        sA[2] = pa[tid + 512]; sA[3] = pa[tid + 768];
    };
    auto ST = [&]() {
        h8v* d = (h8v*)Asb;
        d[tid] = sA[0]; d[tid + 256] = sA[1];
        d[tid + 512] = sA[2]; d[tid + 768] = sA[3];
    };
    LD(0); ST(); LD(1);
    __syncthreads();

    for (int t = 0; t < 16; ++t) {
        const _Float16* bgl = yB + tbe + (size_t)t * 8192;
        // ---- scores: S^T[32k][32q], A = yA frags (LDS), B = qf (regs)
        f16f S = (f16f){};
#pragma unroll
        for (int fs = 0; fs < 16; ++fs) {
            h8v a = *(const h8v*)(Asb + fs * 512 + lane * 8);
            S = MF32(a, qf[fs], S);
        }
        // ---- softmax stats (per-lane col q32; k split across hi halves)
        float mt = S[0];
#pragma unroll
        for (int r = 1; r < 16; ++r) mt = fmaxf(mt, S[r]);
        mt = fmaxf(mt, __shfl_xor(mt, 32));
        if (!__all(mt <= mrun + 8.f)) {       // defer-max: rescale rarely
            float mnew = fmaxf(mrun, mt);
            float alpha = __expf(mrun - mnew);
            lrun *= alpha;
#pragma unroll
            for (int r = 0; r < 16; ++r) {
                int qr = (r & 3) + 8 * (r >> 2) + 4 * hi;
                float ar = __shfl(alpha, qr);
#pragma unroll
                for (int ft = 0; ft < 8; ++ft) ctx[ft][r] *= ar;
            }
            mrun = mnew;
        }
        float p[16], ps = 0.f;
#pragma unroll
        for (int r = 0; r < 16; ++r) { p[r] = __expf(S[r] - mrun); ps += p[r]; }
        ps += __shfl_xor(ps, 32);
        lrun += ps;
        // ---- P -> per-wave LDS (PV A-frag layout)
        {
            _Float16* pw = &Pls[w][0];
#pragma unroll
            for (int r2 = 0; r2 < 4; ++r2) {
                h4v pk = (h4v){(_Float16)p[4 * r2], (_Float16)p[4 * r2 + 1],
                               (_Float16)p[4 * r2 + 2], (_Float16)p[4 * r2 + 3]};
                *(h4v*)(pw + (r2 >> 1) * 512 + (r2 & 1) * 256 + q32 * 8 + hi * 4) = pk;
            }
        }
        // ---- PV: A = P (LDS), B = yB frags (GLOBAL, L1/L2-hot)
#pragma unroll
        for (int ks = 0; ks < 2; ++ks) {
            h8v pa = *(const h8v*)(&Pls[w][ks * 512] + lane * 8);
#pragma unroll
            for (int ft = 0; ft < 8; ++ft) {
                h8v bf = *(const h8v*)(bgl + (ft * 2 + ks) * 512 + lane * 8);
                ctx[ft] = MF32(pa, bf, ctx[ft]);
            }
        }
        // ---- staging rotation
        __syncthreads();
        if (t < 15) {
            ST();
            if (t < 14) LD(t + 2);
            __syncthreads();
        }
    }

    // ---- epilogue: normalized partials + (m, l)
    float linv = 1.f / lrun;
    _Float16* pp = part + ((size_t)z * (BB * LQ) + (size_t)b * LQ + qw) * 256;
#pragma unroll
    for (int r = 0; r < 16; ++r) {
        int qr = (r & 3) + 8 * (r >> 2) + 4 * hi;
        float ir = __shfl(linv, qr);
#pragma unroll
        for (int ft = 0; ft < 8; ++ft)
            pp[(size_t)qr * 256 + ft * 32 + q32] = (_Float16)(ctx[ft][r] * ir);
    }
    if (hi == 0) {
        size_t mi = (size_t)z * (BB * LQ) + (size_t)b * LQ + qw + q32;
        ml[2 * mi + 0] = mrun;
        ml[2 * mi + 1] = lrun;
    }
}

// ---------------------------------------------------------------------------
// out[i][e] = sum_f ctx[i][f] Nt[e][f] + cvec[e]; ctx combined from 4 split-KV
// normalized partials during A-staging (weights l_z e^{m_z-M} / sum).
__global__ __launch_bounds__(256) void gemm2c(
    const _Float16* __restrict__ part, const float* __restrict__ ml,
    const u16* __restrict__ Ntb, const float* __restrict__ cvec,
    float* __restrict__ out)
{
    __shared__ _Float16 Asb[64][40];
    __shared__ float scl[64][4];
    const int tid = threadIdx.x;
    const int w = tid >> 6, lane = tid & 63;
    const int g = lane >> 4, qn = lane & 15;
    const int wr = w >> 1, wc = w & 1;
    const int m0 = blockIdx.x * 64, e0 = blockIdx.y * 256;
    constexpr size_t PL = (size_t)BB * LQ * F;
    constexpr size_t PR = (size_t)BB * LQ;

    if (tid < 64) {
        size_t i = m0 + tid;
        float m0v = ml[2 * i], l0v = ml[2 * i + 1];
        float m1v = ml[2 * (PR + i)], l1v = ml[2 * (PR + i) + 1];
        float m2v = ml[2 * (2 * PR + i)], l2v = ml[2 * (2 * PR + i) + 1];
        float m3v = ml[2 * (3 * PR + i)], l3v = ml[2 * (3 * PR + i) + 1];
        float M = fmaxf(fmaxf(m0v, m1v), fmaxf(m2v, m3v));
        float e0v = __expf(m0v - M), e1v = __expf(m1v - M);
        float e2v = __expf(m2v - M), e3v = __expf(m3v - M);
        float inv = 1.f / (l0v * e0v + l1v * e1v + l2v * e2v + l3v * e3v);
        scl[tid][0] = l0v * e0v * inv;
        scl[tid][1] = l1v * e1v * inv;
        scl[tid][2] = l2v * e2v * inv;
        scl[tid][3] = l3v * e3v * inv;
    }

    f4v acc[2][8];
#pragma unroll
    for (int i = 0; i < 2; ++i)
#pragma unroll
        for (int j = 0; j < 8; ++j) acc[i][j] = (f4v){0.f, 0.f, 0.f, 0.f};

    for (int k0 = 0; k0 < F; k0 += 32) {
        __syncthreads();
        {
            int r = tid & 63, c = (tid >> 6) * 8;
            size_t base = (size_t)(m0 + r) * F + k0 + c;
            h8v p0 = *(const h8v*)(part + base);
            h8v p1 = *(const h8v*)(part + PL + base);
            h8v p2 = *(const h8v*)(part + 2 * PL + base);
            h8v p3 = *(const h8v*)(part + 3 * PL + base);
            float s0 = scl[r][0], s1 = scl[r][1], s2 = scl[r][2], s3 = scl[r][3];
#pragma unroll
            for (int i = 0; i < 8; ++i) {
                float v = (float)p0[i] * s0 + (float)p1[i] * s1 +
                          (float)p2[i] * s2 + (float)p3[i] * s3;
                Asb[r][c + i] = (_Float16)v;
            }
        }
        __syncthreads();

        h8v ah[2], bh[8];
#pragma unroll
        for (int mt = 0; mt < 2; ++mt)
            ah[mt] = *(const h8v*)&Asb[wr * 32 + mt * 16 + qn][g * 8];
        int eb = (e0 + wc * 128) >> 4;
#pragma unroll
        for (int nt = 0; nt < 8; ++nt)
            bh[nt] = *(const h8v*)((const _Float16*)Ntb +
                     (size_t)((k0 >> 5) * 32 + eb + nt) * 512 + lane * 8);
#pragma unroll
        for (int mt = 0; mt < 2; ++mt)
#pragma unroll
            for (int nt = 0; nt < 8; ++nt)
                acc[mt][nt] = MF16(ah[mt], bh[nt], acc[mt][nt]);
    }

#pragma unroll
    for (int mt = 0; mt < 2; ++mt)
#pragma unroll
        for (int nt = 0; nt < 8; ++nt)
#pragma unroll
            for (int r = 0; r < 4; ++r) {
                int gm = m0 + wr * 32 + mt * 16 + 4 * g + r;
                int gn = e0 + wc * 128 + nt * 16 + qn;
                out[(size_t)gm * E + gn] = acc[mt][nt][r] + cvec[gn];
            }
}

// ---------------------------------------------------------------------------
extern "C" void kernel_launch(void* const* d_in, const int* in_sizes, int n_in,
                              void* d_out, int out_size, void* d_ws, size_t ws_size,
                              hipStream_t stream)
{
    const float* x  = (const float*)d_in[0];   // [B,LQ,E]
    const float* y  = (const float*)d_in[1];   // [B,LK,F]
    const float* Wq = (const float*)d_in[2];
    const float* bq = (const float*)d_in[3];
    const float* Wk = (const float*)d_in[4];
    // d_in[5] = bk: per-row constant in scores -> softmax-invariant, unused.
    const float* Wv = (const float*)d_in[6];
    const float* bv = (const float*)d_in[7];
    const float* Wo = (const float*)d_in[8];
    const float* bo = (const float*)d_in[9];
    float* out = (float*)d_out;

    char* ws = (char*)d_ws;
    size_t off = 0;
    auto alloc = [&](size_t bytes) -> char* {
        char* p = ws + off;
        off = (off + bytes + 255) & ~(size_t)255;
        return p;
    };
    u16* Mthb = (u16*)alloc(sizeof(u16) * F * E);
    u16* Mtlb = (u16*)alloc(sizeof(u16) * F * E);
    float* wvec = (float*)alloc(sizeof(float) * F);
    float* cvec = (float*)alloc(sizeof(float) * E);
    u16* Ntb  = (u16*)alloc(sizeof(u16) * E * F);
    _Float16* q16 = (_Float16*)alloc(sizeof(u16) * (size_t)BB * LQ * F);
    _Float16* yA  = (_Float16*)alloc(sizeof(u16) * (size_t)BB * LK * F);
    _Float16* yB  = (_Float16*)alloc(sizeof(u16) * (size_t)BB * LK * F);
    _Float16* part = (_Float16*)alloc(sizeof(u16) * 4 * (size_t)BB * LQ * F);
    float* ml = (float*)alloc(sizeof(float) * 2 * 4 * (size_t)BB * LQ);
    (void)ws_size; (void)in_sizes; (void)n_in; (void)out_size;

    kvec2<<<dim3((F + E) / 4), dim3(256), 0, stream>>>(Wk, bq, bv, Wo, bo, wvec, cvec);
    splitnt<0><<<dim3(F / 64, E / 256), dim3(256), 0, stream>>>(Wk, Wq, Mthb, Mtlb);
    splitnt<2><<<dim3(E / 64, F / 256), dim3(256), 0, stream>>>(Wo, Wv, Ntb, nullptr);
    prep16s<<<dim3(LK / 32, BB), dim3(256), 0, stream>>>(y, yA, yB);
    qprime3<<<dim3(BB * LQ / 64, 2), dim3(256), 0, stream>>>(x, Mthb, Mtlb, wvec, q16);
    flash4<<<dim3(512), dim3(256), 0, stream>>>(q16, yA, yB, part, ml);
    gemm2c<<<dim3(BB * LQ / 64, E / 256), dim3(256), 0, stream>>>(
        part, ml, Ntb, cvec, out);
}

// Round 5
// 174.550 us; speedup vs baseline: 1.5019x; 1.5019x over previous
//
#include <hip/hip_runtime.h>

// CrossAttentionModel on MI355X (gfx950) — round 5.
//
// Math (softmax row-constant invariance + sum(w)=1):
//   Mt[f][e] = sum_a Wk[f][a] Wq[e][a]   (split-bf16 3-pass, ~f32 accurate)
//   wvec[f]  = Wk bq ; cvec[e] = bv Wo + bo
//   q'[i][f] = sum_e x[i][e] Mt[f][e] + wvec[f]  (3-pass, stored fp16)
//   scores   = q' y^T   (fp16 32x32x16 MFMA)
//   out      = (softmax(scores) y) (Wv Wo) + cvec   (fp16 value path)
//
// R5 vs R4: flash reverted to R3 structure (61us proven; R4's global PV-B
// regressed: VGPR 204, occupancy 10%) + defer-max thr=8 only. All weight
// preproc (Mt, Nt, wvec, cvec) merged into ONE 67-block launch (wgemm,
// 64x64 tiles) replacing three serial small-grid kernels.

#define DEV static __device__ __forceinline__

typedef __attribute__((ext_vector_type(8))) short s8v;        // 8 bf16
typedef __attribute__((ext_vector_type(8))) _Float16 h8v;     // 8 fp16
typedef __attribute__((ext_vector_type(4))) _Float16 h4v;
typedef __attribute__((ext_vector_type(4))) float f4v;
typedef __attribute__((ext_vector_type(16))) float f16f;
typedef __attribute__((ext_vector_type(4))) float float4v;
typedef unsigned short u16;
typedef unsigned int u32;

constexpr int BB = 16;
constexpr int LQ = 1024;
constexpr int LK = 2048;
constexpr int E = 512;
constexpr int F = 256;

DEV u16 f2bf(float x) {
    u32 u = __builtin_bit_cast(u32, x);
    u += 0x7fff + ((u >> 16) & 1);
    return (u16)(u >> 16);
}
DEV float bf2f(u16 h) { return __builtin_bit_cast(float, (u32)h << 16); }

DEV f4v MF(s8v a, s8v b, f4v c) {
    return __builtin_amdgcn_mfma_f32_16x16x32_bf16(a, b, c, 0, 0, 0);
}
DEV f4v MF16(h8v a, h8v b, f4v c) {
    return __builtin_amdgcn_mfma_f32_16x16x32_f16(a, b, c, 0, 0, 0);
}
DEV f16f MF32(h8v a, h8v b, f16f c) {
    return __builtin_amdgcn_mfma_f32_32x32x16_f16(a, b, c, 0, 0, 0);
}

// ---------------------------------------------------------------------------
// wgemm: ONE launch for all weight preprocessing.
//   bi 0..31 : Mt[f][e] = sum_a Wk[f][a] Wq[e][a], 64x64 tiles -> split-bf16
//              frag-blocked (Mthb, Mtlb) for qprime3.
//   bi 32..63: Nt[e][f] = sum_a Wo[a][e] Wv[f][a], 64x64 tiles -> fp16
//              frag-blocked (Ntb) for gemm2c.
//   bi 64    : wvec[f] = Wk[f,:] . bq
//   bi 65,66 : cvec[e] = bo[e] + sum_a bv[a] Wo[a][e]
__global__ __launch_bounds__(256) void wgemm(
    const float* __restrict__ Wq, const float* __restrict__ bq,
    const float* __restrict__ Wk, const float* __restrict__ Wv,
    const float* __restrict__ bv, const float* __restrict__ Wo,
    const float* __restrict__ bo,
    u16* __restrict__ Mthb, u16* __restrict__ Mtlb, u16* __restrict__ Ntb,
    float* __restrict__ wvec, float* __restrict__ cvec)
{
    const int bi = blockIdx.x;
    const int tid = threadIdx.x;
    if (bi >= 64) {
        if (bi == 64) {
            const float* r = Wk + (size_t)tid * 512;
            float s = 0.f;
#pragma unroll 4
            for (int a = 0; a < 512; a += 4) {
                float4v v = *(const float4v*)(r + a);
                float4v bb = *(const float4v*)(bq + a);
                s += v[0] * bb[0] + v[1] * bb[1] + v[2] * bb[2] + v[3] * bb[3];
            }
            wvec[tid] = s;
        } else {
            int e = (bi - 65) * 256 + tid;
            float s = bo[e];
#pragma unroll 4
            for (int a = 0; a < 512; ++a) s += bv[a] * Wo[(size_t)a * 512 + e];
            cvec[e] = s;
        }
        return;
    }
    const bool ntm = bi >= 32;
    const int bj = ntm ? bi - 32 : bi;
    const int m0 = ntm ? (bj >> 2) * 64 : (bj >> 3) * 64;
    const int n0 = ntm ? (bj & 3) * 64 : (bj & 7) * 64;
    const float* Ag = ntm ? Wo : Wk;
    const float* Bg = ntm ? Wv : Wq;

    __shared__ u16 Ash[64][40], Asl[64][40];
    __shared__ u16 Bsh[64][40], Bsl[64][40];

    const int w = tid >> 6, lane = tid & 63;
    const int g = lane >> 4, qn = lane & 15;
    const int wr = w & 1, wc = w >> 1;

    f4v acc[2][2];
#pragma unroll
    for (int i = 0; i < 2; ++i)
#pragma unroll
        for (int j = 0; j < 2; ++j) acc[i][j] = (f4v){0.f, 0.f, 0.f, 0.f};

    for (int k0 = 0; k0 < 512; k0 += 32) {
        __syncthreads();
        if (!ntm) {
            int r = tid & 63, c = (tid >> 6) * 8;
            const float* s = Ag + (size_t)(m0 + r) * 512 + k0 + c;
            float4v v0 = *(const float4v*)s, v1 = *(const float4v*)(s + 4);
            short hh[8], ll[8];
#pragma unroll
            for (int i = 0; i < 8; ++i) {
                float x = (i < 4) ? v0[i] : v1[i - 4];
                u16 h = f2bf(x);
                hh[i] = (short)h;
                ll[i] = (short)f2bf(x - bf2f(h));
            }
            *(s8v*)&Ash[r][c] = (s8v){hh[0],hh[1],hh[2],hh[3],hh[4],hh[5],hh[6],hh[7]};
            *(s8v*)&Asl[r][c] = (s8v){ll[0],ll[1],ll[2],ll[3],ll[4],ll[5],ll[6],ll[7]};
        } else {
            int k = tid >> 3, mc = (tid & 7) * 8;
            const float* s = Ag + (size_t)(k0 + k) * 512 + m0 + mc;
            float4v v0 = *(const float4v*)s, v1 = *(const float4v*)(s + 4);
#pragma unroll
            for (int i = 0; i < 8; ++i) {
                float x = (i < 4) ? v0[i] : v1[i - 4];
                u16 h = f2bf(x);
                Ash[mc + i][k] = h;
                Asl[mc + i][k] = f2bf(x - bf2f(h));
            }
        }
        {
            int r = tid & 63, c = (tid >> 6) * 8;
            const float* s = Bg + (size_t)(n0 + r) * 512 + k0 + c;
            float4v v0 = *(const float4v*)s, v1 = *(const float4v*)(s + 4);
            short hh[8], ll[8];
#pragma unroll
            for (int i = 0; i < 8; ++i) {
                float x = (i < 4) ? v0[i] : v1[i - 4];
                u16 h = f2bf(x);
                hh[i] = (short)h;
                ll[i] = (short)f2bf(x - bf2f(h));
            }
            *(s8v*)&Bsh[r][c] = (s8v){hh[0],hh[1],hh[2],hh[3],hh[4],hh[5],hh[6],hh[7]};
            *(s8v*)&Bsl[r][c] = (s8v){ll[0],ll[1],ll[2],ll[3],ll[4],ll[5],ll[6],ll[7]};
        }
        __syncthreads();

        s8v ah[2], al[2], bh[2], bl[2];
#pragma unroll
        for (int mt = 0; mt < 2; ++mt) {
            ah[mt] = *(const s8v*)&Ash[wr * 32 + mt * 16 + qn][g * 8];
            al[mt] = *(const s8v*)&Asl[wr * 32 + mt * 16 + qn][g * 8];
        }
#pragma unroll
        for (int nt = 0; nt < 2; ++nt) {
            bh[nt] = *(const s8v*)&Bsh[wc * 32 + nt * 16 + qn][g * 8];
            bl[nt] = *(const s8v*)&Bsl[wc * 32 + nt * 16 + qn][g * 8];
        }
#pragma unroll
        for (int mt = 0; mt < 2; ++mt)
#pragma unroll
            for (int nt = 0; nt < 2; ++nt) {
                acc[mt][nt] = MF(ah[mt], bh[nt], acc[mt][nt]);
                acc[mt][nt] = MF(ah[mt], bl[nt], acc[mt][nt]);
                acc[mt][nt] = MF(al[mt], bh[nt], acc[mt][nt]);
            }
    }

#pragma unroll
    for (int mt = 0; mt < 2; ++mt)
#pragma unroll
        for (int nt = 0; nt < 2; ++nt)
#pragma unroll
            for (int r = 0; r < 4; ++r) {
                int gm = m0 + wr * 32 + mt * 16 + 4 * g + r;
                int gn = n0 + wc * 32 + nt * 16 + qn;
                float v = acc[mt][nt][r];
                if (!ntm) {
                    size_t off = (size_t)((gn >> 5) * 16 + (gm >> 4)) * 512 +
                                 (gm & 15) * 8 + ((gn >> 3) & 3) * 128 + (gn & 7);
                    u16 h = f2bf(v);
                    Mthb[off] = h;
                    Mtlb[off] = f2bf(v - bf2f(h));
                } else {
                    size_t off = (size_t)((gn >> 5) * 32 + (gm >> 4)) * 512 +
                                 (gm & 15) * 8 + ((gn >> 3) & 3) * 128 + (gn & 7);
                    Ntb[off] = __builtin_bit_cast(u16, (_Float16)v);
                }
            }
}

// ---------------------------------------------------------------------------
// prep16s: y f32 -> fragment-blocked fp16 arrays for flash3.
__global__ __launch_bounds__(256) void prep16s(
    const float* __restrict__ y, _Float16* __restrict__ yA,
    _Float16* __restrict__ yB)
{
    __shared__ float Y[32][260];
    const int tid = threadIdx.x;
    const int b = blockIdx.y, t = blockIdx.x;
    const float* src = y + ((size_t)b * LK + t * 32) * F;
#pragma unroll
    for (int i = 0; i < 8; ++i) {
        int base = i * 1024 + tid * 4;
        int k = base >> 8, f = base & 255;
        *(float4v*)&Y[k][f] = *(const float4v*)(src + base);
    }
    __syncthreads();
    size_t tb = (size_t)(b * 64 + t) * 8192;
#pragma unroll
    for (int i = 0; i < 4; ++i) {
        int c = i * 256 + tid;
        int k = c & 31, hi = (c >> 5) & 1, fs = c >> 6;
        int f0 = fs * 16 + hi * 8;
        float4v v0 = *(const float4v*)&Y[k][f0];
        float4v v1 = *(const float4v*)&Y[k][f0 + 4];
        h8v v;
#pragma unroll
        for (int j = 0; j < 4; ++j) { v[j] = (_Float16)v0[j]; v[4 + j] = (_Float16)v1[j]; }
        *(h8v*)(yA + tb + (size_t)c * 8) = v;
    }
#pragma unroll
    for (int i = 0; i < 4; ++i) {
        int c = i * 256 + tid;
        int fl = c & 31, hi = (c >> 5) & 1, frag = c >> 6;
        int ft = frag >> 1, ks = frag & 1;
        int f = ft * 32 + fl, k0 = ks * 16 + hi * 8;
        h8v v;
#pragma unroll
        for (int j = 0; j < 8; ++j) v[j] = (_Float16)Y[k0 + j][f];
        *(h8v*)(yB + tb + (size_t)c * 8) = v;
    }
}

// ---------------------------------------------------------------------------
// q'[i][f] = sum_e x[i][e] Mt[f][e] + wvec[f] -> fp16.  N-split (grid.y=2).
__global__ __launch_bounds__(256) void qprime3(
    const float* __restrict__ x, const u16* __restrict__ Mthb,
    const u16* __restrict__ Mtlb, const float* __restrict__ wv,
    _Float16* __restrict__ q16)
{
    const int tid = threadIdx.x, w = tid >> 6, lane = tid & 63;
    const int g = lane >> 4, qn = lane & 15;
    const int m0 = blockIdx.x * 64;
    const int nh = blockIdx.y * 8;
    const int arow = m0 + w * 16 + qn;

    f4v acc[8];
#pragma unroll
    for (int n = 0; n < 8; ++n) acc[n] = (f4v){0.f, 0.f, 0.f, 0.f};

    for (int k0 = 0; k0 < 512; k0 += 32) {
        const float* xs = x + (size_t)arow * 512 + k0 + g * 8;
        float4v v0 = *(const float4v*)xs, v1 = *(const float4v*)(xs + 4);
        short hh[8], ll[8];
#pragma unroll
        for (int i = 0; i < 8; ++i) {
            float xv = (i < 4) ? v0[i] : v1[i - 4];
            u16 h = f2bf(xv);
            hh[i] = (short)h;
            ll[i] = (short)f2bf(xv - bf2f(h));
        }
        s8v ah = (s8v){hh[0],hh[1],hh[2],hh[3],hh[4],hh[5],hh[6],hh[7]};
        s8v al = (s8v){ll[0],ll[1],ll[2],ll[3],ll[4],ll[5],ll[6],ll[7]};
        int fb = (k0 >> 5) * 16 + nh;
#pragma unroll
        for (int nt = 0; nt < 8; ++nt) {
            s8v bh = *(const s8v*)(Mthb + (size_t)(fb + nt) * 512 + lane * 8);
            s8v bl = *(const s8v*)(Mtlb + (size_t)(fb + nt) * 512 + lane * 8);
            acc[nt] = MF(ah, bh, acc[nt]);
            acc[nt] = MF(ah, bl, acc[nt]);
            acc[nt] = MF(al, bh, acc[nt]);
        }
    }

#pragma unroll
    for (int nt = 0; nt < 8; ++nt)
#pragma unroll
        for (int r = 0; r < 4; ++r) {
            int row = m0 + w * 16 + 4 * g + r;
            int col = (nh + nt) * 16 + qn;
            q16[(size_t)row * 256 + col] = (_Float16)(acc[nt][r] + wv[col]);
        }
}

// ---------------------------------------------------------------------------
// flash3 (R3 structure): grid 256 flat -> (qb, b, z) XCD-grouped. 512 threads
// = 8 waves x 32 q (256 q/block), 512-key chunk (16 tiles of 32), split-KV=4.
// 32x32x16 fp16 MFMA, swapped scores; P via per-wave LDS; reg-staged
// single-buffer tiles with loads-in-flight; defer-max thr=8 (only R5 change).
__global__ __launch_bounds__(512) void flash3(
    const _Float16* __restrict__ q16, const _Float16* __restrict__ yA,
    const _Float16* __restrict__ yB, _Float16* __restrict__ part,
    float* __restrict__ ml)
{
    __shared__ _Float16 Asb[8192];      // y score-A frags (16KB)
    __shared__ _Float16 Bsb[8192];      // y PV-B frags (16KB)
    __shared__ _Float16 Pls[8][1024];   // per-wave P (2KB each)

    const int tid = threadIdx.x;
    const int w = tid >> 6, lane = tid & 63;
    const int q32 = lane & 31, hi = lane >> 5;

    int id = blockIdx.x;
    int xcd = id & 7, slot = id >> 3;
    int grp = xcd + 8 * (slot >> 2);    // 0..63  (b,z) group, same XCD class
    int qb = slot & 3;
    int b = grp >> 2, z = grp & 3;
    const int qw = qb * 256 + w * 32;

    h8v qf[16];
    {
        const _Float16* qp = q16 + ((size_t)b * LQ + qw + q32) * 256 + hi * 8;
#pragma unroll
        for (int s = 0; s < 16; ++s) qf[s] = *(const h8v*)(qp + s * 16);
    }
    f16f ctx[8];
#pragma unroll
    for (int i = 0; i < 8; ++i) ctx[i] = (f16f){};
    float mrun = -3.0e38f, lrun = 0.f;

    const size_t tbe = (size_t)(b * 64 + z * 16) * 8192;
    h8v sA0, sA1, sB0, sB1;
    auto LD = [&](int t) {
        const h8v* pa = (const h8v*)(yA + tbe + (size_t)t * 8192);
        const h8v* pb = (const h8v*)(yB + tbe + (size_t)t * 8192);
        sA0 = pa[tid]; sA1 = pa[tid + 512];
        sB0 = pb[tid]; sB1 = pb[tid + 512];
    };
    auto ST = [&]() {
        ((h8v*)Asb)[tid] = sA0; ((h8v*)Asb)[tid + 512] = sA1;
        ((h8v*)Bsb)[tid] = sB0; ((h8v*)Bsb)[tid + 512] = sB1;
    };

    LD(0); ST(); LD(1);
    __syncthreads();

    for (int t = 0; t < 16; ++t) {
        // ---- scores: S^T[32k][32q], A = y frags, B = qf
        f16f S = (f16f){};
#pragma unroll
        for (int fs = 0; fs < 16; ++fs) {
            h8v a = *(const h8v*)(Asb + fs * 512 + lane * 8);
            S = MF32(a, qf[fs], S);
        }
        // ---- softmax (per-lane col q = q32), defer-max thr=8
        float mt = S[0];
#pragma unroll
        for (int r = 1; r < 16; ++r) mt = fmaxf(mt, S[r]);
        mt = fmaxf(mt, __shfl_xor(mt, 32));
        if (!__all(mt <= mrun + 8.f)) {
            float mnew = fmaxf(mrun, mt);
            float alpha = __expf(mrun - mnew);
            lrun *= alpha;
#pragma unroll
            for (int r = 0; r < 16; ++r) {
                int qr = (r & 3) + 8 * (r >> 2) + 4 * hi;
                float ar = __shfl(alpha, qr);
#pragma unroll
                for (int ft = 0; ft < 8; ++ft) ctx[ft][r] *= ar;
            }
            mrun = mnew;
        }
        float p[16], ps = 0.f;
#pragma unroll
        for (int r = 0; r < 16; ++r) { p[r] = __expf(S[r] - mrun); ps += p[r]; }
        ps += __shfl_xor(ps, 32);
        lrun += ps;
        // ---- P -> LDS (PV-frag layout)
        {
            _Float16* pw = &Pls[w][0];
#pragma unroll
            for (int r2 = 0; r2 < 4; ++r2) {
                h4v pk = (h4v){(_Float16)p[4 * r2], (_Float16)p[4 * r2 + 1],
                               (_Float16)p[4 * r2 + 2], (_Float16)p[4 * r2 + 3]};
                *(h4v*)(pw + (r2 >> 1) * 512 + (r2 & 1) * 256 + q32 * 8 + hi * 4) = pk;
            }
        }
        // ---- PV: ctx[32q][32f per ft] += P[32q][32k] y[32k][32f]
#pragma unroll
        for (int ks = 0; ks < 2; ++ks) {
            h8v pa = *(const h8v*)(&Pls[w][ks * 512] + lane * 8);
#pragma unroll
            for (int ft = 0; ft < 8; ++ft) {
                h8v bf = *(const h8v*)(Bsb + (ft * 2 + ks) * 512 + lane * 8);
                ctx[ft] = MF32(pa, bf, ctx[ft]);
            }
        }
        // ---- staging rotation
        __syncthreads();
        if (t < 15) {
            ST();
            if (t < 14) LD(t + 2);
            __syncthreads();
        }
    }

    // ---- epilogue: normalized partials + (m, l)
    float linv = 1.f / lrun;
    _Float16* pp = part + ((size_t)z * (BB * LQ) + (size_t)b * LQ + qw) * 256;
#pragma unroll
    for (int r = 0; r < 16; ++r) {
        int qr = (r & 3) + 8 * (r >> 2) + 4 * hi;
        float ir = __shfl(linv, qr);
#pragma unroll
        for (int ft = 0; ft < 8; ++ft)
            pp[(size_t)qr * 256 + ft * 32 + q32] = (_Float16)(ctx[ft][r] * ir);
    }
    if (hi == 0) {
        size_t mi = (size_t)z * (BB * LQ) + (size_t)b * LQ + qw + q32;
        ml[2 * mi + 0] = mrun;
        ml[2 * mi + 1] = lrun;
    }
}

// ---------------------------------------------------------------------------
// out[i][e] = sum_f ctx[i][f] Nt[e][f] + cvec[e]; ctx combined from 4 split-KV
// normalized partials during A-staging (weights l_z e^{m_z-M} / sum).
__global__ __launch_bounds__(256) void gemm2c(
    const _Float16* __restrict__ part, const float* __restrict__ ml,
    const u16* __restrict__ Ntb, const float* __restrict__ cvec,
    float* __restrict__ out)
{
    __shared__ _Float16 Asb[64][40];
    __shared__ float scl[64][4];
    const int tid = threadIdx.x;
    const int w = tid >> 6, lane = tid & 63;
    const int g = lane >> 4, qn = lane & 15;
    const int wr = w >> 1, wc = w & 1;
    const int m0 = blockIdx.x * 64, e0 = blockIdx.y * 256;
    constexpr size_t PL = (size_t)BB * LQ * F;
    constexpr size_t PR = (size_t)BB * LQ;

    if (tid < 64) {
        size_t i = m0 + tid;
        float m0v = ml[2 * i], l0v = ml[2 * i + 1];
        float m1v = ml[2 * (PR + i)], l1v = ml[2 * (PR + i) + 1];
        float m2v = ml[2 * (2 * PR + i)], l2v = ml[2 * (2 * PR + i) + 1];
        float m3v = ml[2 * (3 * PR + i)], l3v = ml[2 * (3 * PR + i) + 1];
        float M = fmaxf(fmaxf(m0v, m1v), fmaxf(m2v, m3v));
        float e0v = __expf(m0v - M), e1v = __expf(m1v - M);
        float e2v = __expf(m2v - M), e3v = __expf(m3v - M);
        float inv = 1.f / (l0v * e0v + l1v * e1v + l2v * e2v + l3v * e3v);
        scl[tid][0] = l0v * e0v * inv;
        scl[tid][1] = l1v * e1v * inv;
        scl[tid][2] = l2v * e2v * inv;
        scl[tid][3] = l3v * e3v * inv;
    }

    f4v acc[2][8];
#pragma unroll
    for (int i = 0; i < 2; ++i)
#pragma unroll
        for (int j = 0; j < 8; ++j) acc[i][j] = (f4v){0.f, 0.f, 0.f, 0.f};

    for (int k0 = 0; k0 < F; k0 += 32) {
        __syncthreads();
        {
            int r = tid & 63, c = (tid >> 6) * 8;
            size_t base = (size_t)(m0 + r) * F + k0 + c;
            h8v p0 = *(const h8v*)(part + base);
            h8v p1 = *(const h8v*)(part + PL + base);
            h8v p2 = *(const h8v*)(part + 2 * PL + base);
            h8v p3 = *(const h8v*)(part + 3 * PL + base);
            float s0 = scl[r][0], s1 = scl[r][1], s2 = scl[r][2], s3 = scl[r][3];
#pragma unroll
            for (int i = 0; i < 8; ++i) {
                float v = (float)p0[i] * s0 + (float)p1[i] * s1 +
                          (float)p2[i] * s2 + (float)p3[i] * s3;
                Asb[r][c + i] = (_Float16)v;
            }
        }
        __syncthreads();

        h8v ah[2], bh[8];
#pragma unroll
        for (int mt = 0; mt < 2; ++mt)
            ah[mt] = *(const h8v*)&Asb[wr * 32 + mt * 16 + qn][g * 8];
        int eb = (e0 + wc * 128) >> 4;
#pragma unroll
        for (int nt = 0; nt < 8; ++nt)
            bh[nt] = *(const h8v*)((const _Float16*)Ntb +
                     (size_t)((k0 >> 5) * 32 + eb + nt) * 512 + lane * 8);
#pragma unroll
        for (int mt = 0; mt < 2; ++mt)
#pragma unroll
            for (int nt = 0; nt < 8; ++nt)
                acc[mt][nt] = MF16(ah[mt], bh[nt], acc[mt][nt]);
    }

#pragma unroll
    for (int mt = 0; mt < 2; ++mt)
#pragma unroll
        for (int nt = 0; nt < 8; ++nt)
#pragma unroll
            for (int r = 0; r < 4; ++r) {
                int gm = m0 + wr * 32 + mt * 16 + 4 * g + r;
                int gn = e0 + wc * 128 + nt * 16 + qn;
                out[(size_t)gm * E + gn] = acc[mt][nt][r] + cvec[gn];
            }
}

// ---------------------------------------------------------------------------
extern "C" void kernel_launch(void* const* d_in, const int* in_sizes, int n_in,
                              void* d_out, int out_size, void* d_ws, size_t ws_size,
                              hipStream_t stream)
{
    const float* x  = (const float*)d_in[0];   // [B,LQ,E]
    const float* y  = (const float*)d_in[1];   // [B,LK,F]
    const float* Wq = (const float*)d_in[2];
    const float* bq = (const float*)d_in[3];
    const float* Wk = (const float*)d_in[4];
    // d_in[5] = bk: per-row constant in scores -> softmax-invariant, unused.
    const float* Wv = (const float*)d_in[6];
    const float* bv = (const float*)d_in[7];
    const float* Wo = (const float*)d_in[8];
    const float* bo = (const float*)d_in[9];
    float* out = (float*)d_out;

    char* ws = (char*)d_ws;
    size_t off = 0;
    auto alloc = [&](size_t bytes) -> char* {
        char* p = ws + off;
        off = (off + bytes + 255) & ~(size_t)255;
        return p;
    };
    u16* Mthb = (u16*)alloc(sizeof(u16) * F * E);
    u16* Mtlb = (u16*)alloc(sizeof(u16) * F * E);
    float* wvec = (float*)alloc(sizeof(float) * F);
    float* cvec = (float*)alloc(sizeof(float) * E);
    u16* Ntb  = (u16*)alloc(sizeof(u16) * E * F);
    _Float16* q16 = (_Float16*)alloc(sizeof(u16) * (size_t)BB * LQ * F);
    _Float16* yA  = (_Float16*)alloc(sizeof(u16) * (size_t)BB * LK * F);
    _Float16* yB  = (_Float16*)alloc(sizeof(u16) * (size_t)BB * LK * F);
    _Float16* part = (_Float16*)alloc(sizeof(u16) * 4 * (size_t)BB * LQ * F);
    float* ml = (float*)alloc(sizeof(float) * 2 * 4 * (size_t)BB * LQ);
    (void)ws_size; (void)in_sizes; (void)n_in; (void)out_size;

    wgemm<<<dim3(67), dim3(256), 0, stream>>>(
        Wq, bq, Wk, Wv, bv, Wo, bo, Mthb, Mtlb, Ntb, wvec, cvec);
    prep16s<<<dim3(LK / 32, BB), dim3(256), 0, stream>>>(y, yA, yB);
    qprime3<<<dim3(BB * LQ / 64, 2), dim3(256), 0, stream>>>(x, Mthb, Mtlb, wvec, q16);
    flash3<<<dim3(256), dim3(512), 0, stream>>>(q16, yA, yB, part, ml);
    gemm2c<<<dim3(BB * LQ / 64, E / 256), dim3(256), 0, stream>>>(
        part, ml, Ntb, cvec, out);
}

// Round 6
// 138.674 us; speedup vs baseline: 1.8905x; 1.2587x over previous
//
#include <hip/hip_runtime.h>

// CrossAttentionModel on MI355X (gfx950) — round 6.
//
// Math (softmax row-constant invariance + sum(w)=1):
//   Mt[f][e] = sum_a Wk[f][a] Wq[e][a]   (split-bf16 3-pass, stored fp16)
//   wvec[f]  = Wk bq ; cvec[e] = bv Wo + bo
//   q'[i][f] = sum_e x[i][e] Mt[f][e] + wvec[f]  (SINGLE-PASS fp16, R6)
//   scores   = q' y^T   (fp16 32x32x16 MFMA)
//   out      = (softmax(scores) y) (Wv Wo) + cvec   (fp16 value path)
//
// R6 vs R5: qprime rewritten (qprime4): single-pass fp16 MFMA (3x fewer
// MFMAs, 2x less B traffic; error budget allows it), x staged through
// double-buffered LDS with coalesced loads, B-frags L1-hot from global.
// flash3 (57us, defer-max) unchanged; wgemm emits fp16 Mhb.

#define DEV static __device__ __forceinline__

typedef __attribute__((ext_vector_type(8))) short s8v;        // 8 bf16
typedef __attribute__((ext_vector_type(8))) _Float16 h8v;     // 8 fp16
typedef __attribute__((ext_vector_type(4))) _Float16 h4v;
typedef __attribute__((ext_vector_type(4))) float f4v;
typedef __attribute__((ext_vector_type(16))) float f16f;
typedef __attribute__((ext_vector_type(4))) float float4v;
typedef unsigned short u16;
typedef unsigned int u32;

constexpr int BB = 16;
constexpr int LQ = 1024;
constexpr int LK = 2048;
constexpr int E = 512;
constexpr int F = 256;

DEV u16 f2bf(float x) {
    u32 u = __builtin_bit_cast(u32, x);
    u += 0x7fff + ((u >> 16) & 1);
    return (u16)(u >> 16);
}
DEV float bf2f(u16 h) { return __builtin_bit_cast(float, (u32)h << 16); }

DEV f4v MF(s8v a, s8v b, f4v c) {
    return __builtin_amdgcn_mfma_f32_16x16x32_bf16(a, b, c, 0, 0, 0);
}
DEV f4v MF16(h8v a, h8v b, f4v c) {
    return __builtin_amdgcn_mfma_f32_16x16x32_f16(a, b, c, 0, 0, 0);
}
DEV f16f MF32(h8v a, h8v b, f16f c) {
    return __builtin_amdgcn_mfma_f32_32x32x16_f16(a, b, c, 0, 0, 0);
}

// ---------------------------------------------------------------------------
// wgemm: ONE launch for all weight preprocessing.
//   bi 0..31 : Mt[f][e] = sum_a Wk[f][a] Wq[e][a] (3-pass split-bf16) ->
//              fp16 frag-blocked Mhb for qprime4.
//   bi 32..63: Nt[e][f] = sum_a Wo[a][e] Wv[f][a] -> fp16 frag-blocked Ntb.
//   bi 64    : wvec[f] = Wk[f,:] . bq
//   bi 65,66 : cvec[e] = bo[e] + sum_a bv[a] Wo[a][e]
__global__ __launch_bounds__(256) void wgemm(
    const float* __restrict__ Wq, const float* __restrict__ bq,
    const float* __restrict__ Wk, const float* __restrict__ Wv,
    const float* __restrict__ bv, const float* __restrict__ Wo,
    const float* __restrict__ bo,
    u16* __restrict__ Mhb, u16* __restrict__ Ntb,
    float* __restrict__ wvec, float* __restrict__ cvec)
{
    const int bi = blockIdx.x;
    const int tid = threadIdx.x;
    if (bi >= 64) {
        if (bi == 64) {
            const float* r = Wk + (size_t)tid * 512;
            float s = 0.f;
#pragma unroll 4
            for (int a = 0; a < 512; a += 4) {
                float4v v = *(const float4v*)(r + a);
                float4v bb = *(const float4v*)(bq + a);
                s += v[0] * bb[0] + v[1] * bb[1] + v[2] * bb[2] + v[3] * bb[3];
            }
            wvec[tid] = s;
        } else {
            int e = (bi - 65) * 256 + tid;
            float s = bo[e];
#pragma unroll 4
            for (int a = 0; a < 512; ++a) s += bv[a] * Wo[(size_t)a * 512 + e];
            cvec[e] = s;
        }
        return;
    }
    const bool ntm = bi >= 32;
    const int bj = ntm ? bi - 32 : bi;
    const int m0 = ntm ? (bj >> 2) * 64 : (bj >> 3) * 64;
    const int n0 = ntm ? (bj & 3) * 64 : (bj & 7) * 64;
    const float* Ag = ntm ? Wo : Wk;
    const float* Bg = ntm ? Wv : Wq;

    __shared__ u16 Ash[64][40], Asl[64][40];
    __shared__ u16 Bsh[64][40], Bsl[64][40];

    const int w = tid >> 6, lane = tid & 63;
    const int g = lane >> 4, qn = lane & 15;
    const int wr = w & 1, wc = w >> 1;

    f4v acc[2][2];
#pragma unroll
    for (int i = 0; i < 2; ++i)
#pragma unroll
        for (int j = 0; j < 2; ++j) acc[i][j] = (f4v){0.f, 0.f, 0.f, 0.f};

    for (int k0 = 0; k0 < 512; k0 += 32) {
        __syncthreads();
        if (!ntm) {
            int r = tid & 63, c = (tid >> 6) * 8;
            const float* s = Ag + (size_t)(m0 + r) * 512 + k0 + c;
            float4v v0 = *(const float4v*)s, v1 = *(const float4v*)(s + 4);
            short hh[8], ll[8];
#pragma unroll
            for (int i = 0; i < 8; ++i) {
                float x = (i < 4) ? v0[i] : v1[i - 4];
                u16 h = f2bf(x);
                hh[i] = (short)h;
                ll[i] = (short)f2bf(x - bf2f(h));
            }
            *(s8v*)&Ash[r][c] = (s8v){hh[0],hh[1],hh[2],hh[3],hh[4],hh[5],hh[6],hh[7]};
            *(s8v*)&Asl[r][c] = (s8v){ll[0],ll[1],ll[2],ll[3],ll[4],ll[5],ll[6],ll[7]};
        } else {
            int k = tid >> 3, mc = (tid & 7) * 8;
            const float* s = Ag + (size_t)(k0 + k) * 512 + m0 + mc;
            float4v v0 = *(const float4v*)s, v1 = *(const float4v*)(s + 4);
#pragma unroll
            for (int i = 0; i < 8; ++i) {
                float x = (i < 4) ? v0[i] : v1[i - 4];
                u16 h = f2bf(x);
                Ash[mc + i][k] = h;
                Asl[mc + i][k] = f2bf(x - bf2f(h));
            }
        }
        {
            int r = tid & 63, c = (tid >> 6) * 8;
            const float* s = Bg + (size_t)(n0 + r) * 512 + k0 + c;
            float4v v0 = *(const float4v*)s, v1 = *(const float4v*)(s + 4);
            short hh[8], ll[8];
#pragma unroll
            for (int i = 0; i < 8; ++i) {
                float x = (i < 4) ? v0[i] : v1[i - 4];
                u16 h = f2bf(x);
                hh[i] = (short)h;
                ll[i] = (short)f2bf(x - bf2f(h));
            }
            *(s8v*)&Bsh[r][c] = (s8v){hh[0],hh[1],hh[2],hh[3],hh[4],hh[5],hh[6],hh[7]};
            *(s8v*)&Bsl[r][c] = (s8v){ll[0],ll[1],ll[2],ll[3],ll[4],ll[5],ll[6],ll[7]};
        }
        __syncthreads();

        s8v ah[2], al[2], bh[2], bl[2];
#pragma unroll
        for (int mt = 0; mt < 2; ++mt) {
            ah[mt] = *(const s8v*)&Ash[wr * 32 + mt * 16 + qn][g * 8];
            al[mt] = *(const s8v*)&Asl[wr * 32 + mt * 16 + qn][g * 8];
        }
#pragma unroll
        for (int nt = 0; nt < 2; ++nt) {
            bh[nt] = *(const s8v*)&Bsh[wc * 32 + nt * 16 + qn][g * 8];
            bl[nt] = *(const s8v*)&Bsl[wc * 32 + nt * 16 + qn][g * 8];
        }
#pragma unroll
        for (int mt = 0; mt < 2; ++mt)
#pragma unroll
            for (int nt = 0; nt < 2; ++nt) {
                acc[mt][nt] = MF(ah[mt], bh[nt], acc[mt][nt]);
                acc[mt][nt] = MF(ah[mt], bl[nt], acc[mt][nt]);
                acc[mt][nt] = MF(al[mt], bh[nt], acc[mt][nt]);
            }
    }

#pragma unroll
    for (int mt = 0; mt < 2; ++mt)
#pragma unroll
        for (int nt = 0; nt < 2; ++nt)
#pragma unroll
            for (int r = 0; r < 4; ++r) {
                int gm = m0 + wr * 32 + mt * 16 + 4 * g + r;
                int gn = n0 + wc * 32 + nt * 16 + qn;
                float v = acc[mt][nt][r];
                if (!ntm) {
                    size_t off = (size_t)((gn >> 5) * 16 + (gm >> 4)) * 512 +
                                 (gm & 15) * 8 + ((gn >> 3) & 3) * 128 + (gn & 7);
                    Mhb[off] = __builtin_bit_cast(u16, (_Float16)v);
                } else {
                    size_t off = (size_t)((gn >> 5) * 32 + (gm >> 4)) * 512 +
                                 (gm & 15) * 8 + ((gn >> 3) & 3) * 128 + (gn & 7);
                    Ntb[off] = __builtin_bit_cast(u16, (_Float16)v);
                }
            }
}

// ---------------------------------------------------------------------------
// prep16s: y f32 -> fragment-blocked fp16 arrays for flash3 (unchanged).
__global__ __launch_bounds__(256) void prep16s(
    const float* __restrict__ y, _Float16* __restrict__ yA,
    _Float16* __restrict__ yB)
{
    __shared__ float Y[32][260];
    const int tid = threadIdx.x;
    const int b = blockIdx.y, t = blockIdx.x;
    const float* src = y + ((size_t)b * LK + t * 32) * F;
#pragma unroll
    for (int i = 0; i < 8; ++i) {
        int base = i * 1024 + tid * 4;
        int k = base >> 8, f = base & 255;
        *(float4v*)&Y[k][f] = *(const float4v*)(src + base);
    }
    __syncthreads();
    size_t tb = (size_t)(b * 64 + t) * 8192;
#pragma unroll
    for (int i = 0; i < 4; ++i) {
        int c = i * 256 + tid;
        int k = c & 31, hi = (c >> 5) & 1, fs = c >> 6;
        int f0 = fs * 16 + hi * 8;
        float4v v0 = *(const float4v*)&Y[k][f0];
        float4v v1 = *(const float4v*)&Y[k][f0 + 4];
        h8v v;
#pragma unroll
        for (int j = 0; j < 4; ++j) { v[j] = (_Float16)v0[j]; v[4 + j] = (_Float16)v1[j]; }
        *(h8v*)(yA + tb + (size_t)c * 8) = v;
    }
#pragma unroll
    for (int i = 0; i < 4; ++i) {
        int c = i * 256 + tid;
        int fl = c & 31, hi = (c >> 5) & 1, frag = c >> 6;
        int ft = frag >> 1, ks = frag & 1;
        int f = ft * 32 + fl, k0 = ks * 16 + hi * 8;
        h8v v;
#pragma unroll
        for (int j = 0; j < 8; ++j) v[j] = (_Float16)Y[k0 + j][f];
        *(h8v*)(yB + tb + (size_t)c * 8) = v;
    }
}

// ---------------------------------------------------------------------------
// qprime4: q'[i][f] = sum_e x[i][e] Mhb[f][e] + wvec[f] -> fp16.
// Single-pass fp16 MFMA. 128x128 tile, grid (128, 2), 256 thr (4 waves,
// each 2 row-frags x 8 col-frags). x staged via double-buffered LDS
// (coalesced 64B/thread loads, fp16 convert once); B-frags direct global
// (1KB frag-linear, L1-hot). Rotation: compute(t) -> ST(t+1) -> LD(t+2) -> bar.
__global__ __launch_bounds__(256) void qprime4(
    const float* __restrict__ x, const u16* __restrict__ Mhb,
    const float* __restrict__ wv, _Float16* __restrict__ q16)
{
    __shared__ _Float16 Xs[2][128][40];
    const int tid = threadIdx.x, w = tid >> 6, lane = tid & 63;
    const int g = lane >> 4, qn = lane & 15;
    const int m0 = blockIdx.x * 128;
    const int nh = blockIdx.y * 8;
    const int srow = tid >> 1, scol = (tid & 1) * 16;
    const _Float16* Mh = (const _Float16*)Mhb;

    f4v acc[2][8];
#pragma unroll
    for (int i = 0; i < 2; ++i)
#pragma unroll
        for (int j = 0; j < 8; ++j) acc[i][j] = (f4v){0.f, 0.f, 0.f, 0.f};

    float4v a0, a1, a2, a3;
    auto LDA = [&](int k0) {
        const float* s = x + (size_t)(m0 + srow) * 512 + k0 + scol;
        a0 = *(const float4v*)s;      a1 = *(const float4v*)(s + 4);
        a2 = *(const float4v*)(s + 8); a3 = *(const float4v*)(s + 12);
    };
    auto STA = [&](int buf) {
        h8v v0, v1;
#pragma unroll
        for (int j = 0; j < 4; ++j) {
            v0[j] = (_Float16)a0[j]; v0[4 + j] = (_Float16)a1[j];
            v1[j] = (_Float16)a2[j]; v1[4 + j] = (_Float16)a3[j];
        }
        *(h8v*)&Xs[buf][srow][scol] = v0;
        *(h8v*)&Xs[buf][srow][scol + 8] = v1;
    };

    LDA(0); STA(0); LDA(32);
    __syncthreads();

    for (int t = 0; t < 16; ++t) {
        const int cur = t & 1;
        h8v af[2];
#pragma unroll
        for (int mt = 0; mt < 2; ++mt)
            af[mt] = *(const h8v*)&Xs[cur][(w * 2 + mt) * 16 + qn][g * 8];
        const int fb = t * 16 + nh;
#pragma unroll
        for (int nt = 0; nt < 8; ++nt) {
            h8v bf = *(const h8v*)(Mh + (size_t)(fb + nt) * 512 + lane * 8);
            acc[0][nt] = MF16(af[0], bf, acc[0][nt]);
            acc[1][nt] = MF16(af[1], bf, acc[1][nt]);
        }
        if (t < 15) {
            STA(cur ^ 1);
            if (t < 14) LDA((t + 2) * 32);
            __syncthreads();
        }
    }

#pragma unroll
    for (int mt = 0; mt < 2; ++mt)
#pragma unroll
        for (int nt = 0; nt < 8; ++nt) {
            int col = (nh + nt) * 16 + qn;
            float wvc = wv[col];
#pragma unroll
            for (int r = 0; r < 4; ++r) {
                int row = m0 + w * 32 + mt * 16 + 4 * g + r;
                q16[(size_t)row * 256 + col] = (_Float16)(acc[mt][nt][r] + wvc);
            }
        }
}

// ---------------------------------------------------------------------------
// flash3 (unchanged from R5, 57us): 8 waves x 32 q, split-KV=4, 32x32x16,
// defer-max thr=8, reg-staged LDS rotation.
__global__ __launch_bounds__(512) void flash3(
    const _Float16* __restrict__ q16, const _Float16* __restrict__ yA,
    const _Float16* __restrict__ yB, _Float16* __restrict__ part,
    float* __restrict__ ml)
{
    __shared__ _Float16 Asb[8192];
    __shared__ _Float16 Bsb[8192];
    __shared__ _Float16 Pls[8][1024];

    const int tid = threadIdx.x;
    const int w = tid >> 6, lane = tid & 63;
    const int q32 = lane & 31, hi = lane >> 5;

    int id = blockIdx.x;
    int xcd = id & 7, slot = id >> 3;
    int grp = xcd + 8 * (slot >> 2);
    int qb = slot & 3;
    int b = grp >> 2, z = grp & 3;
    const int qw = qb * 256 + w * 32;

    h8v qf[16];
    {
        const _Float16* qp = q16 + ((size_t)b * LQ + qw + q32) * 256 + hi * 8;
#pragma unroll
        for (int s = 0; s < 16; ++s) qf[s] = *(const h8v*)(qp + s * 16);
    }
    f16f ctx[8];
#pragma unroll
    for (int i = 0; i < 8; ++i) ctx[i] = (f16f){};
    float mrun = -3.0e38f, lrun = 0.f;

    const size_t tbe = (size_t)(b * 64 + z * 16) * 8192;
    h8v sA0, sA1, sB0, sB1;
    auto LD = [&](int t) {
        const h8v* pa = (const h8v*)(yA + tbe + (size_t)t * 8192);
        const h8v* pb = (const h8v*)(yB + tbe + (size_t)t * 8192);
        sA0 = pa[tid]; sA1 = pa[tid + 512];
        sB0 = pb[tid]; sB1 = pb[tid + 512];
    };
    auto ST = [&]() {
        ((h8v*)Asb)[tid] = sA0; ((h8v*)Asb)[tid + 512] = sA1;
        ((h8v*)Bsb)[tid] = sB0; ((h8v*)Bsb)[tid + 512] = sB1;
    };

    LD(0); ST(); LD(1);
    __syncthreads();

    for (int t = 0; t < 16; ++t) {
        f16f S = (f16f){};
#pragma unroll
        for (int fs = 0; fs < 16; ++fs) {
            h8v a = *(const h8v*)(Asb + fs * 512 + lane * 8);
            S = MF32(a, qf[fs], S);
        }
        float mt = S[0];
#pragma unroll
        for (int r = 1; r < 16; ++r) mt = fmaxf(mt, S[r]);
        mt = fmaxf(mt, __shfl_xor(mt, 32));
        if (!__all(mt <= mrun + 8.f)) {
            float mnew = fmaxf(mrun, mt);
            float alpha = __expf(mrun - mnew);
            lrun *= alpha;
#pragma unroll
            for (int r = 0; r < 16; ++r) {
                int qr = (r & 3) + 8 * (r >> 2) + 4 * hi;
                float ar = __shfl(alpha, qr);
#pragma unroll
                for (int ft = 0; ft < 8; ++ft) ctx[ft][r] *= ar;
            }
            mrun = mnew;
        }
        float p[16], ps = 0.f;
#pragma unroll
        for (int r = 0; r < 16; ++r) { p[r] = __expf(S[r] - mrun); ps += p[r]; }
        ps += __shfl_xor(ps, 32);
        lrun += ps;
        {
            _Float16* pw = &Pls[w][0];
#pragma unroll
            for (int r2 = 0; r2 < 4; ++r2) {
                h4v pk = (h4v){(_Float16)p[4 * r2], (_Float16)p[4 * r2 + 1],
                               (_Float16)p[4 * r2 + 2], (_Float16)p[4 * r2 + 3]};
                *(h4v*)(pw + (r2 >> 1) * 512 + (r2 & 1) * 256 + q32 * 8 + hi * 4) = pk;
            }
        }
#pragma unroll
        for (int ks = 0; ks < 2; ++ks) {
            h8v pa = *(const h8v*)(&Pls[w][ks * 512] + lane * 8);
#pragma unroll
            for (int ft = 0; ft < 8; ++ft) {
                h8v bf = *(const h8v*)(Bsb + (ft * 2 + ks) * 512 + lane * 8);
                ctx[ft] = MF32(pa, bf, ctx[ft]);
            }
        }
        __syncthreads();
        if (t < 15) {
            ST();
            if (t < 14) LD(t + 2);
            __syncthreads();
        }
    }

    float linv = 1.f / lrun;
    _Float16* pp = part + ((size_t)z * (BB * LQ) + (size_t)b * LQ + qw) * 256;
#pragma unroll
    for (int r = 0; r < 16; ++r) {
        int qr = (r & 3) + 8 * (r >> 2) + 4 * hi;
        float ir = __shfl(linv, qr);
#pragma unroll
        for (int ft = 0; ft < 8; ++ft)
            pp[(size_t)qr * 256 + ft * 32 + q32] = (_Float16)(ctx[ft][r] * ir);
    }
    if (hi == 0) {
        size_t mi = (size_t)z * (BB * LQ) + (size_t)b * LQ + qw + q32;
        ml[2 * mi + 0] = mrun;
        ml[2 * mi + 1] = lrun;
    }
}

// ---------------------------------------------------------------------------
// gemm2c (unchanged): out = combine(part) @ Nt + cvec.
__global__ __launch_bounds__(256) void gemm2c(
    const _Float16* __restrict__ part, const float* __restrict__ ml,
    const u16* __restrict__ Ntb, const float* __restrict__ cvec,
    float* __restrict__ out)
{
    __shared__ _Float16 Asb[64][40];
    __shared__ float scl[64][4];
    const int tid = threadIdx.x;
    const int w = tid >> 6, lane = tid & 63;
    const int g = lane >> 4, qn = lane & 15;
    const int wr = w >> 1, wc = w & 1;
    const int m0 = blockIdx.x * 64, e0 = blockIdx.y * 256;
    constexpr size_t PL = (size_t)BB * LQ * F;
    constexpr size_t PR = (size_t)BB * LQ;

    if (tid < 64) {
        size_t i = m0 + tid;
        float m0v = ml[2 * i], l0v = ml[2 * i + 1];
        float m1v = ml[2 * (PR + i)], l1v = ml[2 * (PR + i) + 1];
        float m2v = ml[2 * (2 * PR + i)], l2v = ml[2 * (2 * PR + i) + 1];
        float m3v = ml[2 * (3 * PR + i)], l3v = ml[2 * (3 * PR + i) + 1];
        float M = fmaxf(fmaxf(m0v, m1v), fmaxf(m2v, m3v));
        float e0v = __expf(m0v - M), e1v = __expf(m1v - M);
        float e2v = __expf(m2v - M), e3v = __expf(m3v - M);
        float inv = 1.f / (l0v * e0v + l1v * e1v + l2v * e2v + l3v * e3v);
        scl[tid][0] = l0v * e0v * inv;
        scl[tid][1] = l1v * e1v * inv;
        scl[tid][2] = l2v * e2v * inv;
        scl[tid][3] = l3v * e3v * inv;
    }

    f4v acc[2][8];
#pragma unroll
    for (int i = 0; i < 2; ++i)
#pragma unroll
        for (int j = 0; j < 8; ++j) acc[i][j] = (f4v){0.f, 0.f, 0.f, 0.f};

    for (int k0 = 0; k0 < F; k0 += 32) {
        __syncthreads();
        {
            int r = tid & 63, c = (tid >> 6) * 8;
            size_t base = (size_t)(m0 + r) * F + k0 + c;
            h8v p0 = *(const h8v*)(part + base);
            h8v p1 = *(const h8v*)(part + PL + base);
            h8v p2 = *(const h8v*)(part + 2 * PL + base);
            h8v p3 = *(const h8v*)(part + 3 * PL + base);
            float s0 = scl[r][0], s1 = scl[r][1], s2 = scl[r][2], s3 = scl[r][3];
#pragma unroll
            for (int i = 0; i < 8; ++i) {
                float v = (float)p0[i] * s0 + (float)p1[i] * s1 +
                          (float)p2[i] * s2 + (float)p3[i] * s3;
                Asb[r][c + i] = (_Float16)v;
            }
        }
        __syncthreads();

        h8v ah[2], bh[8];
#pragma unroll
        for (int mt = 0; mt < 2; ++mt)
            ah[mt] = *(const h8v*)&Asb[wr * 32 + mt * 16 + qn][g * 8];
        int eb = (e0 + wc * 128) >> 4;
#pragma unroll
        for (int nt = 0; nt < 8; ++nt)
            bh[nt] = *(const h8v*)((const _Float16*)Ntb +
                     (size_t)((k0 >> 5) * 32 + eb + nt) * 512 + lane * 8);
#pragma unroll
        for (int mt = 0; mt < 2; ++mt)
#pragma unroll
            for (int nt = 0; nt < 8; ++nt)
                acc[mt][nt] = MF16(ah[mt], bh[nt], acc[mt][nt]);
    }

#pragma unroll
    for (int mt = 0; mt < 2; ++mt)
#pragma unroll
        for (int nt = 0; nt < 8; ++nt)
#pragma unroll
            for (int r = 0; r < 4; ++r) {
                int gm = m0 + wr * 32 + mt * 16 + 4 * g + r;
                int gn = e0 + wc * 128 + nt * 16 + qn;
                out[(size_t)gm * E + gn] = acc[mt][nt][r] + cvec[gn];
            }
}

// ---------------------------------------------------------------------------
extern "C" void kernel_launch(void* const* d_in, const int* in_sizes, int n_in,
                              void* d_out, int out_size, void* d_ws, size_t ws_size,
                              hipStream_t stream)
{
    const float* x  = (const float*)d_in[0];   // [B,LQ,E]
    const float* y  = (const float*)d_in[1];   // [B,LK,F]
    const float* Wq = (const float*)d_in[2];
    const float* bq = (const float*)d_in[3];
    const float* Wk = (const float*)d_in[4];
    // d_in[5] = bk: per-row constant in scores -> softmax-invariant, unused.
    const float* Wv = (const float*)d_in[6];
    const float* bv = (const float*)d_in[7];
    const float* Wo = (const float*)d_in[8];
    const float* bo = (const float*)d_in[9];
    float* out = (float*)d_out;

    char* ws = (char*)d_ws;
    size_t off = 0;
    auto alloc = [&](size_t bytes) -> char* {
        char* p = ws + off;
        off = (off + bytes + 255) & ~(size_t)255;
        return p;
    };
    u16* Mhb  = (u16*)alloc(sizeof(u16) * F * E);
    float* wvec = (float*)alloc(sizeof(float) * F);
    float* cvec = (float*)alloc(sizeof(float) * E);
    u16* Ntb  = (u16*)alloc(sizeof(u16) * E * F);
    _Float16* q16 = (_Float16*)alloc(sizeof(u16) * (size_t)BB * LQ * F);
    _Float16* yA  = (_Float16*)alloc(sizeof(u16) * (size_t)BB * LK * F);
    _Float16* yB  = (_Float16*)alloc(sizeof(u16) * (size_t)BB * LK * F);
    _Float16* part = (_Float16*)alloc(sizeof(u16) * 4 * (size_t)BB * LQ * F);
    float* ml = (float*)alloc(sizeof(float) * 2 * 4 * (size_t)BB * LQ);
    (void)ws_size; (void)in_sizes; (void)n_in; (void)out_size;

    wgemm<<<dim3(67), dim3(256), 0, stream>>>(
        Wq, bq, Wk, Wv, bv, Wo, bo, Mhb, Ntb, wvec, cvec);
    prep16s<<<dim3(LK / 32, BB), dim3(256), 0, stream>>>(y, yA, yB);
    qprime4<<<dim3(BB * LQ / 128, 2), dim3(256), 0, stream>>>(x, Mhb, wvec, q16);
    flash3<<<dim3(256), dim3(512), 0, stream>>>(q16, yA, yB, part, ml);
    gemm2c<<<dim3(BB * LQ / 64, E / 256), dim3(256), 0, stream>>>(
        part, ml, Ntb, cvec, out);
}

// Round 7
// 137.281 us; speedup vs baseline: 1.9096x; 1.0101x over previous
//
#include <hip/hip_runtime.h>

// CrossAttentionModel on MI355X (gfx950) — round 7.
//
// Math (softmax row-constant invariance + sum(w)=1):
//   Mt[f][e] = sum_a Wk[f][a] Wq[e][a]   (split-bf16 3-pass, stored fp16)
//   wvec[f]  = Wk bq ; cvec[e] = bv Wo + bo
//   q'[i][f] = sum_e x[i][e] Mt[f][e] + wvec[f]  (single-pass fp16)
//   scores   = q' y^T   (fp16 32x32x16 MFMA)
//   out      = (softmax(scores) y) (Wv Wo) + cvec   (fp16 value path)
//
// R7 vs R6: flash5 = flash3 with global_load_lds double-buffered 64-key
// super-tiles: barriers 32 -> 8, staging regs/ds_writes deleted, prefetch
// overlaps compute (m97 pattern; yA/yB frag arrays are lane-linear so gll's
// wave-uniform-base+lane*16 constraint is satisfied). LDS 144KB/block.
// wgemm+prep16s fused into one launch (prew). Numerics unchanged.

#define DEV static __device__ __forceinline__

typedef __attribute__((ext_vector_type(8))) short s8v;        // 8 bf16
typedef __attribute__((ext_vector_type(8))) _Float16 h8v;     // 8 fp16
typedef __attribute__((ext_vector_type(4))) _Float16 h4v;
typedef __attribute__((ext_vector_type(4))) float f4v;
typedef __attribute__((ext_vector_type(16))) float f16f;
typedef __attribute__((ext_vector_type(4))) float float4v;
typedef unsigned short u16;
typedef unsigned int u32;

constexpr int BB = 16;
constexpr int LQ = 1024;
constexpr int LK = 2048;
constexpr int E = 512;
constexpr int F = 256;

DEV u16 f2bf(float x) {
    u32 u = __builtin_bit_cast(u32, x);
    u += 0x7fff + ((u >> 16) & 1);
    return (u16)(u >> 16);
}
DEV float bf2f(u16 h) { return __builtin_bit_cast(float, (u32)h << 16); }

DEV f4v MF(s8v a, s8v b, f4v c) {
    return __builtin_amdgcn_mfma_f32_16x16x32_bf16(a, b, c, 0, 0, 0);
}
DEV f4v MF16(h8v a, h8v b, f4v c) {
    return __builtin_amdgcn_mfma_f32_16x16x32_f16(a, b, c, 0, 0, 0);
}
DEV f16f MF32(h8v a, h8v b, f16f c) {
    return __builtin_amdgcn_mfma_f32_32x32x16_f16(a, b, c, 0, 0, 0);
}

// global -> LDS async copy, 16 bytes per lane.
DEV void gll16(const _Float16* g, _Float16* l) {
    __builtin_amdgcn_global_load_lds(
        (const __attribute__((address_space(1))) u32*)g,
        (__attribute__((address_space(3))) u32*)l, 16, 0, 0);
}

// ---------------------------------------------------------------------------
// prew: fused weight preprocessing + y fragment prep (independent work).
//   bi 0..1023   : prep16s body — y f32 -> yA (score-A frags) + yB (PV-B frags)
//   bi 1024..1087: wgemm 64x64 tiles (Mt -> Mhb fp16 frag-blocked,
//                  Nt -> Ntb fp16 frag-blocked), split-bf16 3-pass internally
//   bi 1088      : wvec ; bi 1089,1090: cvec
__global__ __launch_bounds__(256) void prew(
    const float* __restrict__ y, _Float16* __restrict__ yA,
    _Float16* __restrict__ yB,
    const float* __restrict__ Wq, const float* __restrict__ bq,
    const float* __restrict__ Wk, const float* __restrict__ Wv,
    const float* __restrict__ bv, const float* __restrict__ Wo,
    const float* __restrict__ bo,
    u16* __restrict__ Mhb, u16* __restrict__ Ntb,
    float* __restrict__ wvec, float* __restrict__ cvec)
{
    __shared__ __align__(16) char smem[33536];
    const int tid = threadIdx.x;
    const int bi = blockIdx.x;

    if (bi < 1024) {
        // ---------------- prep16s ----------------
        float (*Y)[260] = (float(*)[260])smem;
        const int b = bi >> 6, t = bi & 63;
        const float* src = y + ((size_t)b * LK + t * 32) * F;
#pragma unroll
        for (int i = 0; i < 8; ++i) {
            int base = i * 1024 + tid * 4;
            int k = base >> 8, f = base & 255;
            *(float4v*)&Y[k][f] = *(const float4v*)(src + base);
        }
        __syncthreads();
        size_t tb = (size_t)(b * 64 + t) * 8192;
#pragma unroll
        for (int i = 0; i < 4; ++i) {
            int c = i * 256 + tid;
            int k = c & 31, hi = (c >> 5) & 1, fs = c >> 6;
            int f0 = fs * 16 + hi * 8;
            float4v v0 = *(const float4v*)&Y[k][f0];
            float4v v1 = *(const float4v*)&Y[k][f0 + 4];
            h8v v;
#pragma unroll
            for (int j = 0; j < 4; ++j) { v[j] = (_Float16)v0[j]; v[4 + j] = (_Float16)v1[j]; }
            *(h8v*)(yA + tb + (size_t)c * 8) = v;
        }
#pragma unroll
        for (int i = 0; i < 4; ++i) {
            int c = i * 256 + tid;
            int fl = c & 31, hi = (c >> 5) & 1, frag = c >> 6;
            int ft = frag >> 1, ks = frag & 1;
            int f = ft * 32 + fl, k0 = ks * 16 + hi * 8;
            h8v v;
#pragma unroll
            for (int j = 0; j < 8; ++j) v[j] = (_Float16)Y[k0 + j][f];
            *(h8v*)(yB + tb + (size_t)c * 8) = v;
        }
        return;
    }

    const int wb = bi - 1024;
    if (wb >= 64) {
        if (wb == 64) {
            const float* r = Wk + (size_t)tid * 512;
            float s = 0.f;
#pragma unroll 4
            for (int a = 0; a < 512; a += 4) {
                float4v v = *(const float4v*)(r + a);
                float4v bb = *(const float4v*)(bq + a);
                s += v[0] * bb[0] + v[1] * bb[1] + v[2] * bb[2] + v[3] * bb[3];
            }
            wvec[tid] = s;
        } else {
            int e = (wb - 65) * 256 + tid;
            float s = bo[e];
#pragma unroll 4
            for (int a = 0; a < 512; ++a) s += bv[a] * Wo[(size_t)a * 512 + e];
            cvec[e] = s;
        }
        return;
    }

    // ---------------- wgemm 64x64 tile ----------------
    const bool ntm = wb >= 32;
    const int bj = ntm ? wb - 32 : wb;
    const int m0 = ntm ? (bj >> 2) * 64 : (bj >> 3) * 64;
    const int n0 = ntm ? (bj & 3) * 64 : (bj & 7) * 64;
    const float* Ag = ntm ? Wo : Wk;
    const float* Bg = ntm ? Wv : Wq;

    u16 (*Ash)[40] = (u16(*)[40])(smem);
    u16 (*Asl)[40] = (u16(*)[40])(smem + 5120);
    u16 (*Bsh)[40] = (u16(*)[40])(smem + 10240);
    u16 (*Bsl)[40] = (u16(*)[40])(smem + 15360);

    const int w = tid >> 6, lane = tid & 63;
    const int g = lane >> 4, qn = lane & 15;
    const int wr = w & 1, wc = w >> 1;

    f4v acc[2][2];
#pragma unroll
    for (int i = 0; i < 2; ++i)
#pragma unroll
        for (int j = 0; j < 2; ++j) acc[i][j] = (f4v){0.f, 0.f, 0.f, 0.f};

    for (int k0 = 0; k0 < 512; k0 += 32) {
        __syncthreads();
        if (!ntm) {
            int r = tid & 63, c = (tid >> 6) * 8;
            const float* s = Ag + (size_t)(m0 + r) * 512 + k0 + c;
            float4v v0 = *(const float4v*)s, v1 = *(const float4v*)(s + 4);
            short hh[8], ll[8];
#pragma unroll
            for (int i = 0; i < 8; ++i) {
                float x = (i < 4) ? v0[i] : v1[i - 4];
                u16 h = f2bf(x);
                hh[i] = (short)h;
                ll[i] = (short)f2bf(x - bf2f(h));
            }
            *(s8v*)&Ash[r][c] = (s8v){hh[0],hh[1],hh[2],hh[3],hh[4],hh[5],hh[6],hh[7]};
            *(s8v*)&Asl[r][c] = (s8v){ll[0],ll[1],ll[2],ll[3],ll[4],ll[5],ll[6],ll[7]};
        } else {
            int k = tid >> 3, mc = (tid & 7) * 8;
            const float* s = Ag + (size_t)(k0 + k) * 512 + m0 + mc;
            float4v v0 = *(const float4v*)s, v1 = *(const float4v*)(s + 4);
#pragma unroll
            for (int i = 0; i < 8; ++i) {
                float x = (i < 4) ? v0[i] : v1[i - 4];
                u16 h = f2bf(x);
                Ash[mc + i][k] = h;
                Asl[mc + i][k] = f2bf(x - bf2f(h));
            }
        }
        {
            int r = tid & 63, c = (tid >> 6) * 8;
            const float* s = Bg + (size_t)(n0 + r) * 512 + k0 + c;
            float4v v0 = *(const float4v*)s, v1 = *(const float4v*)(s + 4);
            short hh[8], ll[8];
#pragma unroll
            for (int i = 0; i < 8; ++i) {
                float x = (i < 4) ? v0[i] : v1[i - 4];
                u16 h = f2bf(x);
                hh[i] = (short)h;
                ll[i] = (short)f2bf(x - bf2f(h));
            }
            *(s8v*)&Bsh[r][c] = (s8v){hh[0],hh[1],hh[2],hh[3],hh[4],hh[5],hh[6],hh[7]};
            *(s8v*)&Bsl[r][c] = (s8v){ll[0],ll[1],ll[2],ll[3],ll[4],ll[5],ll[6],ll[7]};
        }
        __syncthreads();

        s8v ah[2], al[2], bh[2], bl[2];
#pragma unroll
        for (int mt = 0; mt < 2; ++mt) {
            ah[mt] = *(const s8v*)&Ash[wr * 32 + mt * 16 + qn][g * 8];
            al[mt] = *(const s8v*)&Asl[wr * 32 + mt * 16 + qn][g * 8];
        }
#pragma unroll
        for (int nt = 0; nt < 2; ++nt) {
            bh[nt] = *(const s8v*)&Bsh[wc * 32 + nt * 16 + qn][g * 8];
            bl[nt] = *(const s8v*)&Bsl[wc * 32 + nt * 16 + qn][g * 8];
        }
#pragma unroll
        for (int mt = 0; mt < 2; ++mt)
#pragma unroll
            for (int nt = 0; nt < 2; ++nt) {
                acc[mt][nt] = MF(ah[mt], bh[nt], acc[mt][nt]);
                acc[mt][nt] = MF(ah[mt], bl[nt], acc[mt][nt]);
                acc[mt][nt] = MF(al[mt], bh[nt], acc[mt][nt]);
            }
    }

#pragma unroll
    for (int mt = 0; mt < 2; ++mt)
#pragma unroll
        for (int nt = 0; nt < 2; ++nt)
#pragma unroll
            for (int r = 0; r < 4; ++r) {
                int gm = m0 + wr * 32 + mt * 16 + 4 * g + r;
                int gn = n0 + wc * 32 + nt * 16 + qn;
                float v = acc[mt][nt][r];
                if (!ntm) {
                    size_t off = (size_t)((gn >> 5) * 16 + (gm >> 4)) * 512 +
                                 (gm & 15) * 8 + ((gn >> 3) & 3) * 128 + (gn & 7);
                    Mhb[off] = __builtin_bit_cast(u16, (_Float16)v);
                } else {
                    size_t off = (size_t)((gn >> 5) * 32 + (gm >> 4)) * 512 +
                                 (gm & 15) * 8 + ((gn >> 3) & 3) * 128 + (gn & 7);
                    Ntb[off] = __builtin_bit_cast(u16, (_Float16)v);
                }
            }
}

// ---------------------------------------------------------------------------
// qprime4 (unchanged): q' = x @ Mt + wvec -> fp16, single-pass.
__global__ __launch_bounds__(256) void qprime4(
    const float* __restrict__ x, const u16* __restrict__ Mhb,
    const float* __restrict__ wv, _Float16* __restrict__ q16)
{
    __shared__ _Float16 Xs[2][128][40];
    const int tid = threadIdx.x, w = tid >> 6, lane = tid & 63;
    const int g = lane >> 4, qn = lane & 15;
    const int m0 = blockIdx.x * 128;
    const int nh = blockIdx.y * 8;
    const int srow = tid >> 1, scol = (tid & 1) * 16;
    const _Float16* Mh = (const _Float16*)Mhb;

    f4v acc[2][8];
#pragma unroll
    for (int i = 0; i < 2; ++i)
#pragma unroll
        for (int j = 0; j < 8; ++j) acc[i][j] = (f4v){0.f, 0.f, 0.f, 0.f};

    float4v a0, a1, a2, a3;
    auto LDA = [&](int k0) {
        const float* s = x + (size_t)(m0 + srow) * 512 + k0 + scol;
        a0 = *(const float4v*)s;      a1 = *(const float4v*)(s + 4);
        a2 = *(const float4v*)(s + 8); a3 = *(const float4v*)(s + 12);
    };
    auto STA = [&](int buf) {
        h8v v0, v1;
#pragma unroll
        for (int j = 0; j < 4; ++j) {
            v0[j] = (_Float16)a0[j]; v0[4 + j] = (_Float16)a1[j];
            v1[j] = (_Float16)a2[j]; v1[4 + j] = (_Float16)a3[j];
        }
        *(h8v*)&Xs[buf][srow][scol] = v0;
        *(h8v*)&Xs[buf][srow][scol + 8] = v1;
    };

    LDA(0); STA(0); LDA(32);
    __syncthreads();

    for (int t = 0; t < 16; ++t) {
        const int cur = t & 1;
        h8v af[2];
#pragma unroll
        for (int mt = 0; mt < 2; ++mt)
            af[mt] = *(const h8v*)&Xs[cur][(w * 2 + mt) * 16 + qn][g * 8];
        const int fb = t * 16 + nh;
#pragma unroll
        for (int nt = 0; nt < 8; ++nt) {
            h8v bf = *(const h8v*)(Mh + (size_t)(fb + nt) * 512 + lane * 8);
            acc[0][nt] = MF16(af[0], bf, acc[0][nt]);
            acc[1][nt] = MF16(af[1], bf, acc[1][nt]);
        }
        if (t < 15) {
            STA(cur ^ 1);
            if (t < 14) LDA((t + 2) * 32);
            __syncthreads();
        }
    }

#pragma unroll
    for (int mt = 0; mt < 2; ++mt)
#pragma unroll
        for (int nt = 0; nt < 8; ++nt) {
            int col = (nh + nt) * 16 + qn;
            float wvc = wv[col];
#pragma unroll
            for (int r = 0; r < 4; ++r) {
                int row = m0 + w * 32 + mt * 16 + 4 * g + r;
                q16[(size_t)row * 256 + col] = (_Float16)(acc[mt][nt][r] + wvc);
            }
        }
}

// ---------------------------------------------------------------------------
// flash5: flash3 structure + gll double-buffered 64-key super-tiles.
// grid 256 (qb 0..3, b, z 0..3) XCD-grouped; 512 thr = 8 waves x 32 q;
// 8 supers x 2 tiles; 1 barrier per super; defer-max thr=8.
__global__ __launch_bounds__(512) void flash5(
    const _Float16* __restrict__ q16, const _Float16* __restrict__ yA,
    const _Float16* __restrict__ yB, _Float16* __restrict__ part,
    float* __restrict__ ml)
{
    __shared__ _Float16 Asb[2][2][8192];   // 64KB: [buf][tile][frags]
    __shared__ _Float16 Bsb[2][2][8192];   // 64KB
    __shared__ _Float16 Pls[8][1024];      // 16KB

    const int tid = threadIdx.x;
    const int w = tid >> 6, lane = tid & 63;
    const int q32 = lane & 31, hi = lane >> 5;

    int id = blockIdx.x;
    int xcd = id & 7, slot = id >> 3;
    int grp = xcd + 8 * (slot >> 2);
    int qb = slot & 3;
    int b = grp >> 2, z = grp & 3;
    const int qw = qb * 256 + w * 32;

    h8v qf[16];
    {
        const _Float16* qp = q16 + ((size_t)b * LQ + qw + q32) * 256 + hi * 8;
#pragma unroll
        for (int s = 0; s < 16; ++s) qf[s] = *(const h8v*)(qp + s * 16);
    }
    f16f ctx[8];
#pragma unroll
    for (int i = 0; i < 8; ++i) ctx[i] = (f16f){};
    float mrun = -3.0e38f, lrun = 0.f;

    const size_t tbe = (size_t)(b * 64 + z * 16) * 8192;

    auto STAGE = [&](int sup, int buf) {
#pragma unroll
        for (int j = 0; j < 2; ++j) {
            const _Float16* ga = yA + tbe + (size_t)(sup * 2 + j) * 8192 + tid * 8;
            const _Float16* gb = yB + tbe + (size_t)(sup * 2 + j) * 8192 + tid * 8;
            gll16(ga,        &Asb[buf][j][tid * 8]);
            gll16(ga + 4096, &Asb[buf][j][tid * 8 + 4096]);
            gll16(gb,        &Bsb[buf][j][tid * 8]);
            gll16(gb + 4096, &Bsb[buf][j][tid * 8 + 4096]);
        }
    };

    STAGE(0, 0);
    __syncthreads();

    int buf = 0;
    for (int s = 0; s < 8; ++s) {
        if (s < 7) STAGE(s + 1, buf ^ 1);
#pragma unroll
        for (int j = 0; j < 2; ++j) {
            const _Float16* Ap = &Asb[buf][j][0];
            const _Float16* Bp = &Bsb[buf][j][0];
            // ---- scores: S^T[32k][32q], A = y frags (LDS), B = qf (regs)
            f16f S = (f16f){};
#pragma unroll
            for (int fs = 0; fs < 16; ++fs) {
                h8v a = *(const h8v*)(Ap + fs * 512 + lane * 8);
                S = MF32(a, qf[fs], S);
            }
            // ---- softmax (per-lane col q = q32), defer-max thr=8
            float mt = S[0];
#pragma unroll
            for (int r = 1; r < 16; ++r) mt = fmaxf(mt, S[r]);
            mt = fmaxf(mt, __shfl_xor(mt, 32));
            if (!__all(mt <= mrun + 8.f)) {
                float mnew = fmaxf(mrun, mt);
                float alpha = __expf(mrun - mnew);
                lrun *= alpha;
#pragma unroll
                for (int r = 0; r < 16; ++r) {
                    int qr = (r & 3) + 8 * (r >> 2) + 4 * hi;
                    float ar = __shfl(alpha, qr);
#pragma unroll
                    for (int ft = 0; ft < 8; ++ft) ctx[ft][r] *= ar;
                }
                mrun = mnew;
            }
            float p[16], ps = 0.f;
#pragma unroll
            for (int r = 0; r < 16; ++r) { p[r] = __expf(S[r] - mrun); ps += p[r]; }
            ps += __shfl_xor(ps, 32);
            lrun += ps;
            // ---- P -> per-wave LDS (PV A-frag layout)
            {
                _Float16* pw = &Pls[w][0];
#pragma unroll
                for (int r2 = 0; r2 < 4; ++r2) {
                    h4v pk = (h4v){(_Float16)p[4 * r2], (_Float16)p[4 * r2 + 1],
                                   (_Float16)p[4 * r2 + 2], (_Float16)p[4 * r2 + 3]};
                    *(h4v*)(pw + (r2 >> 1) * 512 + (r2 & 1) * 256 + q32 * 8 + hi * 4) = pk;
                }
            }
            // ---- PV: ctx += P[32q][32k] y[32k][32f]
#pragma unroll
            for (int ks = 0; ks < 2; ++ks) {
                h8v pa = *(const h8v*)(&Pls[w][ks * 512] + lane * 8);
#pragma unroll
                for (int ft = 0; ft < 8; ++ft) {
                    h8v bf = *(const h8v*)(Bp + (ft * 2 + ks) * 512 + lane * 8);
                    ctx[ft] = MF32(pa, bf, ctx[ft]);
                }
            }
        }
        __syncthreads();
        buf ^= 1;
    }

    // ---- epilogue: normalized partials + (m, l)
    float linv = 1.f / lrun;
    _Float16* pp = part + ((size_t)z * (BB * LQ) + (size_t)b * LQ + qw) * 256;
#pragma unroll
    for (int r = 0; r < 16; ++r) {
        int qr = (r & 3) + 8 * (r >> 2) + 4 * hi;
        float ir = __shfl(linv, qr);
#pragma unroll
        for (int ft = 0; ft < 8; ++ft)
            pp[(size_t)qr * 256 + ft * 32 + q32] = (_Float16)(ctx[ft][r] * ir);
    }
    if (hi == 0) {
        size_t mi = (size_t)z * (BB * LQ) + (size_t)b * LQ + qw + q32;
        ml[2 * mi + 0] = mrun;
        ml[2 * mi + 1] = lrun;
    }
}

// ---------------------------------------------------------------------------
// gemm2c (unchanged): out = combine(part) @ Nt + cvec.
__global__ __launch_bounds__(256) void gemm2c(
    const _Float16* __restrict__ part, const float* __restrict__ ml,
    const u16* __restrict__ Ntb, const float* __restrict__ cvec,
    float* __restrict__ out)
{
    __shared__ _Float16 Asb[64][40];
    __shared__ float scl[64][4];
    const int tid = threadIdx.x;
    const int w = tid >> 6, lane = tid & 63;
    const int g = lane >> 4, qn = lane & 15;
    const int wr = w >> 1, wc = w & 1;
    const int m0 = blockIdx.x * 64, e0 = blockIdx.y * 256;
    constexpr size_t PL = (size_t)BB * LQ * F;
    constexpr size_t PR = (size_t)BB * LQ;

    if (tid < 64) {
        size_t i = m0 + tid;
        float m0v = ml[2 * i], l0v = ml[2 * i + 1];
        float m1v = ml[2 * (PR + i)], l1v = ml[2 * (PR + i) + 1];
        float m2v = ml[2 * (2 * PR + i)], l2v = ml[2 * (2 * PR + i) + 1];
        float m3v = ml[2 * (3 * PR + i)], l3v = ml[2 * (3 * PR + i) + 1];
        float M = fmaxf(fmaxf(m0v, m1v), fmaxf(m2v, m3v));
        float e0v = __expf(m0v - M), e1v = __expf(m1v - M);
        float e2v = __expf(m2v - M), e3v = __expf(m3v - M);
        float inv = 1.f / (l0v * e0v + l1v * e1v + l2v * e2v + l3v * e3v);
        scl[tid][0] = l0v * e0v * inv;
        scl[tid][1] = l1v * e1v * inv;
        scl[tid][2] = l2v * e2v * inv;
        scl[tid][3] = l3v * e3v * inv;
    }

    f4v acc[2][8];
#pragma unroll
    for (int i = 0; i < 2; ++i)
#pragma unroll
        for (int j = 0; j < 8; ++j) acc[i][j] = (f4v){0.f, 0.f, 0.f, 0.f};

    for (int k0 = 0; k0 < F; k0 += 32) {
        __syncthreads();
        {
            int r = tid & 63, c = (tid >> 6) * 8;
            size_t base = (size_t)(m0 + r) * F + k0 + c;
            h8v p0 = *(const h8v*)(part + base);
            h8v p1 = *(const h8v*)(part + PL + base);
            h8v p2 = *(const h8v*)(part + 2 * PL + base);
            h8v p3 = *(const h8v*)(part + 3 * PL + base);
            float s0 = scl[r][0], s1 = scl[r][1], s2 = scl[r][2], s3 = scl[r][3];
#pragma unroll
            for (int i = 0; i < 8; ++i) {
                float v = (float)p0[i] * s0 + (float)p1[i] * s1 +
                          (float)p2[i] * s2 + (float)p3[i] * s3;
                Asb[r][c + i] = (_Float16)v;
            }
        }
        __syncthreads();

        h8v ah[2], bh[8];
#pragma unroll
        for (int mt = 0; mt < 2; ++mt)
            ah[mt] = *(const h8v*)&Asb[wr * 32 + mt * 16 + qn][g * 8];
        int eb = (e0 + wc * 128) >> 4;
#pragma unroll
        for (int nt = 0; nt < 8; ++nt)
            bh[nt] = *(const h8v*)((const _Float16*)Ntb +
                     (size_t)((k0 >> 5) * 32 + eb + nt) * 512 + lane * 8);
#pragma unroll
        for (int mt = 0; mt < 2; ++mt)
#pragma unroll
            for (int nt = 0; nt < 8; ++nt)
                acc[mt][nt] = MF16(ah[mt], bh[nt], acc[mt][nt]);
    }

#pragma unroll
    for (int mt = 0; mt < 2; ++mt)
#pragma unroll
        for (int nt = 0; nt < 8; ++nt)
#pragma unroll
            for (int r = 0; r < 4; ++r) {
                int gm = m0 + wr * 32 + mt * 16 + 4 * g + r;
                int gn = e0 + wc * 128 + nt * 16 + qn;
                out[(size_t)gm * E + gn] = acc[mt][nt][r] + cvec[gn];
            }
}

// ---------------------------------------------------------------------------
extern "C" void kernel_launch(void* const* d_in, const int* in_sizes, int n_in,
                              void* d_out, int out_size, void* d_ws, size_t ws_size,
                              hipStream_t stream)
{
    const float* x  = (const float*)d_in[0];   // [B,LQ,E]
    const float* y  = (const float*)d_in[1];   // [B,LK,F]
    const float* Wq = (const float*)d_in[2];
    const float* bq = (const float*)d_in[3];
    const float* Wk = (const float*)d_in[4];
    // d_in[5] = bk: per-row constant in scores -> softmax-invariant, unused.
    const float* Wv = (const float*)d_in[6];
    const float* bv = (const float*)d_in[7];
    const float* Wo = (const float*)d_in[8];
    const float* bo = (const float*)d_in[9];
    float* out = (float*)d_out;

    char* ws = (char*)d_ws;
    size_t off = 0;
    auto alloc = [&](size_t bytes) -> char* {
        char* p = ws + off;
        off = (off + bytes + 255) & ~(size_t)255;
        return p;
    };
    u16* Mhb  = (u16*)alloc(sizeof(u16) * F * E);
    float* wvec = (float*)alloc(sizeof(float) * F);
    float* cvec = (float*)alloc(sizeof(float) * E);
    u16* Ntb  = (u16*)alloc(sizeof(u16) * E * F);
    _Float16* q16 = (_Float16*)alloc(sizeof(u16) * (size_t)BB * LQ * F);
    _Float16* yA  = (_Float16*)alloc(sizeof(u16) * (size_t)BB * LK * F);
    _Float16* yB  = (_Float16*)alloc(sizeof(u16) * (size_t)BB * LK * F);
    _Float16* part = (_Float16*)alloc(sizeof(u16) * 4 * (size_t)BB * LQ * F);
    float* ml = (float*)alloc(sizeof(float) * 2 * 4 * (size_t)BB * LQ);
    (void)ws_size; (void)in_sizes; (void)n_in; (void)out_size;

    prew<<<dim3(1091), dim3(256), 0, stream>>>(
        y, yA, yB, Wq, bq, Wk, Wv, bv, Wo, bo, Mhb, Ntb, wvec, cvec);
    qprime4<<<dim3(BB * LQ / 128, 2), dim3(256), 0, stream>>>(x, Mhb, wvec, q16);
    flash5<<<dim3(256), dim3(512), 0, stream>>>(q16, yA, yB, part, ml);
    gemm2c<<<dim3(BB * LQ / 64, E / 256), dim3(256), 0, stream>>>(
        part, ml, Ntb, cvec, out);
}

// Round 9
// 137.178 us; speedup vs baseline: 1.9111x; 1.0007x over previous
//
#include <hip/hip_runtime.h>

// CrossAttentionModel on MI355X (gfx950) — round 9 (R8 plan, compile fix).
//
// Math (softmax row-constant invariance + sum(w)=1):
//   Mt[f][e] = sum_a Wk[f][a] Wq[e][a]   (split-bf16 3-pass, stored fp16)
//   wvec[f]  = Wk bq ; cvec[e] = bv Wo + bo
//   q'[i][f] = (sum_e x[i][e] Mt[f][e] + wvec[f]) * log2(e)   (fp16)
//   scores'  = q' y^T  (base-2 softmax domain; 32x32x16 fp16 MFMA)
//   out      = (softmax2(scores') y) (Wv Wo) + cvec
//
// flash6: (1) score accumulation split into 2 independent MFMA chains,
// (2) P assembled IN-REGISTER via cvt_pkrtz + shfl_xor(32) + per-lane select
// (Pls LDS deleted -> no bank conflicts, no write->read serialization),
// (3) exp2-domain softmax. qprime5: 64-row tiles, grid(256,2).
// Fix vs R8: cvt_pkrtz returns __fp16x2 -> capture as auto, bit_cast to u32.

#define DEV static __device__ __forceinline__

typedef __attribute__((ext_vector_type(8))) short s8v;        // 8 bf16
typedef __attribute__((ext_vector_type(8))) _Float16 h8v;     // 8 fp16
typedef __attribute__((ext_vector_type(4))) float f4v;
typedef __attribute__((ext_vector_type(16))) float f16f;
typedef __attribute__((ext_vector_type(4))) float float4v;
typedef __attribute__((ext_vector_type(4))) unsigned int u32x4;
typedef unsigned short u16;
typedef unsigned int u32;

constexpr int BB = 16;
constexpr int LQ = 1024;
constexpr int LK = 2048;
constexpr int E = 512;
constexpr int F = 256;

DEV u16 f2bf(float x) {
    u32 u = __builtin_bit_cast(u32, x);
    u += 0x7fff + ((u >> 16) & 1);
    return (u16)(u >> 16);
}
DEV float bf2f(u16 h) { return __builtin_bit_cast(float, (u32)h << 16); }

DEV f4v MF(s8v a, s8v b, f4v c) {
    return __builtin_amdgcn_mfma_f32_16x16x32_bf16(a, b, c, 0, 0, 0);
}
DEV f4v MF16(h8v a, h8v b, f4v c) {
    return __builtin_amdgcn_mfma_f32_16x16x32_f16(a, b, c, 0, 0, 0);
}
DEV f16f MF32(h8v a, h8v b, f16f c) {
    return __builtin_amdgcn_mfma_f32_32x32x16_f16(a, b, c, 0, 0, 0);
}
DEV u32 pkh(float a, float b) {               // pack 2 f32 -> 2 f16 (RTZ), 1 op
    auto t = __builtin_amdgcn_cvt_pkrtz(a, b);    // __fp16 ext_vector(2)
    return __builtin_bit_cast(u32, t);
}

// global -> LDS async copy, 16 bytes per lane.
DEV void gll16(const _Float16* g, _Float16* l) {
    __builtin_amdgcn_global_load_lds(
        (const __attribute__((address_space(1))) u32*)g,
        (__attribute__((address_space(3))) u32*)l, 16, 0, 0);
}

// ---------------------------------------------------------------------------
// prew: fused weight preprocessing + y fragment prep.
__global__ __launch_bounds__(256) void prew(
    const float* __restrict__ y, _Float16* __restrict__ yA,
    _Float16* __restrict__ yB,
    const float* __restrict__ Wq, const float* __restrict__ bq,
    const float* __restrict__ Wk, const float* __restrict__ Wv,
    const float* __restrict__ bv, const float* __restrict__ Wo,
    const float* __restrict__ bo,
    u16* __restrict__ Mhb, u16* __restrict__ Ntb,
    float* __restrict__ wvec, float* __restrict__ cvec)
{
    __shared__ __align__(16) char smem[33536];
    const int tid = threadIdx.x;
    const int bi = blockIdx.x;

    if (bi < 1024) {
        float (*Y)[260] = (float(*)[260])smem;
        const int b = bi >> 6, t = bi & 63;
        const float* src = y + ((size_t)b * LK + t * 32) * F;
#pragma unroll
        for (int i = 0; i < 8; ++i) {
            int base = i * 1024 + tid * 4;
            int k = base >> 8, f = base & 255;
            *(float4v*)&Y[k][f] = *(const float4v*)(src + base);
        }
        __syncthreads();
        size_t tb = (size_t)(b * 64 + t) * 8192;
#pragma unroll
        for (int i = 0; i < 4; ++i) {
            int c = i * 256 + tid;
            int k = c & 31, hi = (c >> 5) & 1, fs = c >> 6;
            int f0 = fs * 16 + hi * 8;
            float4v v0 = *(const float4v*)&Y[k][f0];
            float4v v1 = *(const float4v*)&Y[k][f0 + 4];
            h8v v;
#pragma unroll
            for (int j = 0; j < 4; ++j) { v[j] = (_Float16)v0[j]; v[4 + j] = (_Float16)v1[j]; }
            *(h8v*)(yA + tb + (size_t)c * 8) = v;
        }
#pragma unroll
        for (int i = 0; i < 4; ++i) {
            int c = i * 256 + tid;
            int fl = c & 31, hi = (c >> 5) & 1, frag = c >> 6;
            int ft = frag >> 1, ks = frag & 1;
            int f = ft * 32 + fl, k0 = ks * 16 + hi * 8;
            h8v v;
#pragma unroll
            for (int j = 0; j < 8; ++j) v[j] = (_Float16)Y[k0 + j][f];
            *(h8v*)(yB + tb + (size_t)c * 8) = v;
        }
        return;
    }

    const int wb = bi - 1024;
    if (wb >= 64) {
        if (wb == 64) {
            const float* r = Wk + (size_t)tid * 512;
            float s = 0.f;
#pragma unroll 4
            for (int a = 0; a < 512; a += 4) {
                float4v v = *(const float4v*)(r + a);
                float4v bb = *(const float4v*)(bq + a);
                s += v[0] * bb[0] + v[1] * bb[1] + v[2] * bb[2] + v[3] * bb[3];
            }
            wvec[tid] = s;
        } else {
            int e = (wb - 65) * 256 + tid;
            float s = bo[e];
#pragma unroll 4
            for (int a = 0; a < 512; ++a) s += bv[a] * Wo[(size_t)a * 512 + e];
            cvec[e] = s;
        }
        return;
    }

    const bool ntm = wb >= 32;
    const int bj = ntm ? wb - 32 : wb;
    const int m0 = ntm ? (bj >> 2) * 64 : (bj >> 3) * 64;
    const int n0 = ntm ? (bj & 3) * 64 : (bj & 7) * 64;
    const float* Ag = ntm ? Wo : Wk;
    const float* Bg = ntm ? Wv : Wq;

    u16 (*Ash)[40] = (u16(*)[40])(smem);
    u16 (*Asl)[40] = (u16(*)[40])(smem + 5120);
    u16 (*Bsh)[40] = (u16(*)[40])(smem + 10240);
    u16 (*Bsl)[40] = (u16(*)[40])(smem + 15360);

    const int w = tid >> 6, lane = tid & 63;
    const int g = lane >> 4, qn = lane & 15;
    const int wr = w & 1, wc = w >> 1;

    f4v acc[2][2];
#pragma unroll
    for (int i = 0; i < 2; ++i)
#pragma unroll
        for (int j = 0; j < 2; ++j) acc[i][j] = (f4v){0.f, 0.f, 0.f, 0.f};

    for (int k0 = 0; k0 < 512; k0 += 32) {
        __syncthreads();
        if (!ntm) {
            int r = tid & 63, c = (tid >> 6) * 8;
            const float* s = Ag + (size_t)(m0 + r) * 512 + k0 + c;
            float4v v0 = *(const float4v*)s, v1 = *(const float4v*)(s + 4);
            short hh[8], ll[8];
#pragma unroll
            for (int i = 0; i < 8; ++i) {
                float x = (i < 4) ? v0[i] : v1[i - 4];
                u16 h = f2bf(x);
                hh[i] = (short)h;
                ll[i] = (short)f2bf(x - bf2f(h));
            }
            *(s8v*)&Ash[r][c] = (s8v){hh[0],hh[1],hh[2],hh[3],hh[4],hh[5],hh[6],hh[7]};
            *(s8v*)&Asl[r][c] = (s8v){ll[0],ll[1],ll[2],ll[3],ll[4],ll[5],ll[6],ll[7]};
        } else {
            int k = tid >> 3, mc = (tid & 7) * 8;
            const float* s = Ag + (size_t)(k0 + k) * 512 + m0 + mc;
            float4v v0 = *(const float4v*)s, v1 = *(const float4v*)(s + 4);
#pragma unroll
            for (int i = 0; i < 8; ++i) {
                float x = (i < 4) ? v0[i] : v1[i - 4];
                u16 h = f2bf(x);
                Ash[mc + i][k] = h;
                Asl[mc + i][k] = f2bf(x - bf2f(h));
            }
        }
        {
            int r = tid & 63, c = (tid >> 6) * 8;
            const float* s = Bg + (size_t)(n0 + r) * 512 + k0 + c;
            float4v v0 = *(const float4v*)s, v1 = *(const float4v*)(s + 4);
            short hh[8], ll[8];
#pragma unroll
            for (int i = 0; i < 8; ++i) {
                float x = (i < 4) ? v0[i] : v1[i - 4];
                u16 h = f2bf(x);
                hh[i] = (short)h;
                ll[i] = (short)f2bf(x - bf2f(h));
            }
            *(s8v*)&Bsh[r][c] = (s8v){hh[0],hh[1],hh[2],hh[3],hh[4],hh[5],hh[6],hh[7]};
            *(s8v*)&Bsl[r][c] = (s8v){ll[0],ll[1],ll[2],ll[3],ll[4],ll[5],ll[6],ll[7]};
        }
        __syncthreads();

        s8v ah[2], al[2], bh[2], bl[2];
#pragma unroll
        for (int mt = 0; mt < 2; ++mt) {
            ah[mt] = *(const s8v*)&Ash[wr * 32 + mt * 16 + qn][g * 8];
            al[mt] = *(const s8v*)&Asl[wr * 32 + mt * 16 + qn][g * 8];
        }
#pragma unroll
        for (int nt = 0; nt < 2; ++nt) {
            bh[nt] = *(const s8v*)&Bsh[wc * 32 + nt * 16 + qn][g * 8];
            bl[nt] = *(const s8v*)&Bsl[wc * 32 + nt * 16 + qn][g * 8];
        }
#pragma unroll
        for (int mt = 0; mt < 2; ++mt)
#pragma unroll
            for (int nt = 0; nt < 2; ++nt) {
                acc[mt][nt] = MF(ah[mt], bh[nt], acc[mt][nt]);
                acc[mt][nt] = MF(ah[mt], bl[nt], acc[mt][nt]);
                acc[mt][nt] = MF(al[mt], bh[nt], acc[mt][nt]);
            }
    }

#pragma unroll
    for (int mt = 0; mt < 2; ++mt)
#pragma unroll
        for (int nt = 0; nt < 2; ++nt)
#pragma unroll
            for (int r = 0; r < 4; ++r) {
                int gm = m0 + wr * 32 + mt * 16 + 4 * g + r;
                int gn = n0 + wc * 32 + nt * 16 + qn;
                float v = acc[mt][nt][r];
                if (!ntm) {
                    size_t off = (size_t)((gn >> 5) * 16 + (gm >> 4)) * 512 +
                                 (gm & 15) * 8 + ((gn >> 3) & 3) * 128 + (gn & 7);
                    Mhb[off] = __builtin_bit_cast(u16, (_Float16)v);
                } else {
                    size_t off = (size_t)((gn >> 5) * 32 + (gm >> 4)) * 512 +
                                 (gm & 15) * 8 + ((gn >> 3) & 3) * 128 + (gn & 7);
                    Ntb[off] = __builtin_bit_cast(u16, (_Float16)v);
                }
            }
}

// ---------------------------------------------------------------------------
// qprime5: q' = (x @ Mt + wvec) * log2e -> fp16. 64-row tiles, grid (256, 2).
__global__ __launch_bounds__(256) void qprime5(
    const float* __restrict__ x, const u16* __restrict__ Mhb,
    const float* __restrict__ wv, _Float16* __restrict__ q16)
{
    __shared__ _Float16 Xs[2][64][40];
    const int tid = threadIdx.x, w = tid >> 6, lane = tid & 63;
    const int g = lane >> 4, qn = lane & 15;
    const int m0 = blockIdx.x * 64;
    const int nh = blockIdx.y * 8;
    const int srow = tid >> 2, scol = (tid & 3) * 8;
    const _Float16* Mh = (const _Float16*)Mhb;

    f4v acc[8];
#pragma unroll
    for (int n = 0; n < 8; ++n) acc[n] = (f4v){0.f, 0.f, 0.f, 0.f};

    float4v a0, a1;
    auto LDA = [&](int k0) {
        const float* s = x + (size_t)(m0 + srow) * 512 + k0 + scol;
        a0 = *(const float4v*)s;
        a1 = *(const float4v*)(s + 4);
    };
    auto STA = [&](int buf) {
        h8v v;
#pragma unroll
        for (int j = 0; j < 4; ++j) { v[j] = (_Float16)a0[j]; v[4 + j] = (_Float16)a1[j]; }
        *(h8v*)&Xs[buf][srow][scol] = v;
    };

    LDA(0); STA(0); LDA(32);
    __syncthreads();

    for (int t = 0; t < 16; ++t) {
        const int cur = t & 1;
        h8v af = *(const h8v*)&Xs[cur][w * 16 + qn][g * 8];
        const int fb = t * 16 + nh;
#pragma unroll
        for (int nt = 0; nt < 8; ++nt) {
            h8v bf = *(const h8v*)(Mh + (size_t)(fb + nt) * 512 + lane * 8);
            acc[nt] = MF16(af, bf, acc[nt]);
        }
        if (t < 15) {
            STA(cur ^ 1);
            if (t < 14) LDA((t + 2) * 32);
            __syncthreads();
        }
    }

#pragma unroll
    for (int nt = 0; nt < 8; ++nt) {
        int col = (nh + nt) * 16 + qn;
        float wvc = wv[col];
#pragma unroll
        for (int r = 0; r < 4; ++r) {
            int row = m0 + w * 16 + 4 * g + r;
            q16[(size_t)row * 256 + col] =
                (_Float16)((acc[nt][r] + wvc) * 1.44269504f);
        }
    }
}

// ---------------------------------------------------------------------------
// flash6: S 2-chain split, in-register P, exp2 softmax, no Pls.
// grid 256 (qb, b, z) XCD-grouped; 512 thr = 8 waves x 32 q; gll dbuf
// 64-key supers; defer-max thr=11.54 (log2 units). LDS 128KB.
__global__ __launch_bounds__(512) void flash6(
    const _Float16* __restrict__ q16, const _Float16* __restrict__ yA,
    const _Float16* __restrict__ yB, _Float16* __restrict__ part,
    float* __restrict__ ml)
{
    __shared__ _Float16 Asb[2][2][8192];   // 64KB
    __shared__ _Float16 Bsb[2][2][8192];   // 64KB

    const int tid = threadIdx.x;
    const int lane = tid & 63;
    const int q32 = lane & 31;
    const int hi = lane >> 5;

    int id = blockIdx.x;
    int xcd = id & 7, slot = id >> 3;
    int grp = xcd + 8 * (slot >> 2);
    int qb = slot & 3;
    int b = grp >> 2, z = grp & 3;
    const int qw = qb * 256 + (tid >> 6) * 32;

    h8v qf[16];
    {
        const _Float16* qp = q16 + ((size_t)b * LQ + qw + q32) * 256 + hi * 8;
#pragma unroll
        for (int s = 0; s < 16; ++s) qf[s] = *(const h8v*)(qp + s * 16);
    }
    f16f ctx[8];
#pragma unroll
    for (int i = 0; i < 8; ++i) ctx[i] = (f16f){};
    float mrun = -3.0e38f, lrun = 0.f;

    const size_t tbe = (size_t)(b * 64 + z * 16) * 8192;

    auto STAGE = [&](int sup, int buf) {
#pragma unroll
        for (int j = 0; j < 2; ++j) {
            const _Float16* ga = yA + tbe + (size_t)(sup * 2 + j) * 8192 + tid * 8;
            const _Float16* gb = yB + tbe + (size_t)(sup * 2 + j) * 8192 + tid * 8;
            gll16(ga,        &Asb[buf][j][tid * 8]);
            gll16(ga + 4096, &Asb[buf][j][tid * 8 + 4096]);
            gll16(gb,        &Bsb[buf][j][tid * 8]);
            gll16(gb + 4096, &Bsb[buf][j][tid * 8 + 4096]);
        }
    };

    STAGE(0, 0);
    __syncthreads();

    int buf = 0;
    for (int s = 0; s < 8; ++s) {
        if (s < 7) STAGE(s + 1, buf ^ 1);
#pragma unroll
        for (int j = 0; j < 2; ++j) {
            const _Float16* Ap = &Asb[buf][j][0];
            const _Float16* Bp = &Bsb[buf][j][0];
            // ---- scores: two independent MFMA chains, merged once
            f16f Sa = (f16f){}, Sb = (f16f){};
#pragma unroll
            for (int fs = 0; fs < 16; fs += 2) {
                h8v a0 = *(const h8v*)(Ap + fs * 512 + lane * 8);
                h8v a1 = *(const h8v*)(Ap + (fs + 1) * 512 + lane * 8);
                Sa = MF32(a0, qf[fs], Sa);
                Sb = MF32(a1, qf[fs + 1], Sb);
            }
            f16f S = Sa + Sb;
            // ---- softmax stats (base-2), defer-max thr = 8*log2e
            float mt = fmaxf(S[0], S[1]);
#pragma unroll
            for (int r = 2; r < 16; ++r) mt = fmaxf(mt, S[r]);
            mt = fmaxf(mt, __shfl_xor(mt, 32));
            if (!__all(mt <= mrun + 11.5416f)) {
                float mnew = fmaxf(mrun, mt);
                float alpha = exp2f(mrun - mnew);
                lrun *= alpha;
#pragma unroll
                for (int r = 0; r < 16; ++r) {
                    int qr = (r & 3) + 8 * (r >> 2) + 4 * hi;
                    float ar = __shfl(alpha, qr);
#pragma unroll
                    for (int ft = 0; ft < 8; ++ft) ctx[ft][r] *= ar;
                }
                mrun = mnew;
            }
            float p[16], ps = 0.f;
#pragma unroll
            for (int r = 0; r < 16; ++r) { p[r] = exp2f(S[r] - mrun); ps += p[r]; }
            ps += __shfl_xor(ps, 32);
            lrun += ps;
            // ---- P -> PV A-frags IN REGISTER (replaces Pls LDS roundtrip).
            // p[r] holds P[q32][k=(r&3)+8*(r>>2)+4*hi]; A-frag for 32x32x16
            // needs lane(q32,hi) to hold k_local hi*8+0..7 per 16-k slab.
            {
                u32 X0 = pkh(p[0], p[1]),   X1 = pkh(p[2], p[3]);
                u32 Y0 = pkh(p[4], p[5]),   Y1 = pkh(p[6], p[7]);
                u32 Z0 = pkh(p[8], p[9]),   Z1 = pkh(p[10], p[11]);
                u32 W0 = pkh(p[12], p[13]), W1 = pkh(p[14], p[15]);
                u32 M0 = hi ? X0 : Y0, M1 = hi ? X1 : Y1;   // what partner needs
                u32 N0 = hi ? Z0 : W0, N1 = hi ? Z1 : W1;
                u32 sM0 = __shfl_xor(M0, 32), sM1 = __shfl_xor(M1, 32);
                u32 sN0 = __shfl_xor(N0, 32), sN1 = __shfl_xor(N1, 32);
                u32x4 A0u = (u32x4){hi ? sM0 : X0, hi ? sM1 : X1,
                                    hi ? Y0 : sM0, hi ? Y1 : sM1};
                u32x4 A1u = (u32x4){hi ? sN0 : Z0, hi ? sN1 : Z1,
                                    hi ? W0 : sN0, hi ? W1 : sN1};
                h8v pa0 = __builtin_bit_cast(h8v, A0u);
                h8v pa1 = __builtin_bit_cast(h8v, A1u);
                // ---- PV: ctx += P[32q][32k] y[32k][32f]
#pragma unroll
                for (int ft = 0; ft < 8; ++ft) {
                    h8v bf = *(const h8v*)(Bp + (ft * 2 + 0) * 512 + lane * 8);
                    ctx[ft] = MF32(pa0, bf, ctx[ft]);
                }
#pragma unroll
                for (int ft = 0; ft < 8; ++ft) {
                    h8v bf = *(const h8v*)(Bp + (ft * 2 + 1) * 512 + lane * 8);
                    ctx[ft] = MF32(pa1, bf, ctx[ft]);
                }
            }
        }
        __syncthreads();
        buf ^= 1;
    }

    // ---- epilogue: normalized partials + (m, l)  (m,l in base-2 domain)
    float linv = 1.f / lrun;
    _Float16* pp = part + ((size_t)z * (BB * LQ) + (size_t)b * LQ + qw) * 256;
#pragma unroll
    for (int r = 0; r < 16; ++r) {
        int qr = (r & 3) + 8 * (r >> 2) + 4 * hi;
        float ir = __shfl(linv, qr);
#pragma unroll
        for (int ft = 0; ft < 8; ++ft)
            pp[(size_t)qr * 256 + ft * 32 + q32] = (_Float16)(ctx[ft][r] * ir);
    }
    if (hi == 0) {
        size_t mi = (size_t)z * (BB * LQ) + (size_t)b * LQ + qw + q32;
        ml[2 * mi + 0] = mrun;
        ml[2 * mi + 1] = lrun;
    }
}

// ---------------------------------------------------------------------------
// gemm2c: out = combine(part) @ Nt + cvec. Combine weights in base-2 domain.
__global__ __launch_bounds__(256) void gemm2c(
    const _Float16* __restrict__ part, const float* __restrict__ ml,
    const u16* __restrict__ Ntb, const float* __restrict__ cvec,
    float* __restrict__ out)
{
    __shared__ _Float16 Asb[64][40];
    __shared__ float scl[64][4];
    const int tid = threadIdx.x;
    const int w = tid >> 6, lane = tid & 63;
    const int g = lane >> 4, qn = lane & 15;
    const int wr = w >> 1, wc = w & 1;
    const int m0 = blockIdx.x * 64, e0 = blockIdx.y * 256;
    constexpr size_t PL = (size_t)BB * LQ * F;
    constexpr size_t PR = (size_t)BB * LQ;

    if (tid < 64) {
        size_t i = m0 + tid;
        float m0v = ml[2 * i], l0v = ml[2 * i + 1];
        float m1v = ml[2 * (PR + i)], l1v = ml[2 * (PR + i) + 1];
        float m2v = ml[2 * (2 * PR + i)], l2v = ml[2 * (2 * PR + i) + 1];
        float m3v = ml[2 * (3 * PR + i)], l3v = ml[2 * (3 * PR + i) + 1];
        float M = fmaxf(fmaxf(m0v, m1v), fmaxf(m2v, m3v));
        float e0v = exp2f(m0v - M), e1v = exp2f(m1v - M);
        float e2v = exp2f(m2v - M), e3v = exp2f(m3v - M);
        float inv = 1.f / (l0v * e0v + l1v * e1v + l2v * e2v + l3v * e3v);
        scl[tid][0] = l0v * e0v * inv;
        scl[tid][1] = l1v * e1v * inv;
        scl[tid][2] = l2v * e2v * inv;
        scl[tid][3] = l3v * e3v * inv;
    }

    f4v acc[2][8];
#pragma unroll
    for (int i = 0; i < 2; ++i)
#pragma unroll
        for (int j = 0; j < 8; ++j) acc[i][j] = (f4v){0.f, 0.f, 0.f, 0.f};

    for (int k0 = 0; k0 < F; k0 += 32) {
        __syncthreads();
        {
            int r = tid & 63, c = (tid >> 6) * 8;
            size_t base = (size_t)(m0 + r) * F + k0 + c;
            h8v p0 = *(const h8v*)(part + base);
            h8v p1 = *(const h8v*)(part + PL + base);
            h8v p2 = *(const h8v*)(part + 2 * PL + base);
            h8v p3 = *(const h8v*)(part + 3 * PL + base);
            float s0 = scl[r][0], s1 = scl[r][1], s2 = scl[r][2], s3 = scl[r][3];
#pragma unroll
            for (int i = 0; i < 8; ++i) {
                float v = (float)p0[i] * s0 + (float)p1[i] * s1 +
                          (float)p2[i] * s2 + (float)p3[i] * s3;
                Asb[r][c + i] = (_Float16)v;
            }
        }
        __syncthreads();

        h8v ah[2], bh[8];
#pragma unroll
        for (int mt = 0; mt < 2; ++mt)
            ah[mt] = *(const h8v*)&Asb[wr * 32 + mt * 16 + qn][g * 8];
        int eb = (e0 + wc * 128) >> 4;
#pragma unroll
        for (int nt = 0; nt < 8; ++nt)
            bh[nt] = *(const h8v*)((const _Float16*)Ntb +
                     (size_t)((k0 >> 5) * 32 + eb + nt) * 512 + lane * 8);
#pragma unroll
        for (int mt = 0; mt < 2; ++mt)
#pragma unroll
            for (int nt = 0; nt < 8; ++nt)
                acc[mt][nt] = MF16(ah[mt], bh[nt], acc[mt][nt]);
    }

#pragma unroll
    for (int mt = 0; mt < 2; ++mt)
#pragma unroll
        for (int nt = 0; nt < 8; ++nt)
#pragma unroll
            for (int r = 0; r < 4; ++r) {
                int gm = m0 + wr * 32 + mt * 16 + 4 * g + r;
                int gn = e0 + wc * 128 + nt * 16 + qn;
                out[(size_t)gm * E + gn] = acc[mt][nt][r] + cvec[gn];
            }
}

// ---------------------------------------------------------------------------
extern "C" void kernel_launch(void* const* d_in, const int* in_sizes, int n_in,
                              void* d_out, int out_size, void* d_ws, size_t ws_size,
                              hipStream_t stream)
{
    const float* x  = (const float*)d_in[0];   // [B,LQ,E]
    const float* y  = (const float*)d_in[1];   // [B,LK,F]
    const float* Wq = (const float*)d_in[2];
    const float* bq = (const float*)d_in[3];
    const float* Wk = (const float*)d_in[4];
    // d_in[5] = bk: per-row constant in scores -> softmax-invariant, unused.
    const float* Wv = (const float*)d_in[6];
    const float* bv = (const float*)d_in[7];
    const float* Wo = (const float*)d_in[8];
    const float* bo = (const float*)d_in[9];
    float* out = (float*)d_out;

    char* ws = (char*)d_ws;
    size_t off = 0;
    auto alloc = [&](size_t bytes) -> char* {
        char* p = ws + off;
        off = (off + bytes + 255) & ~(size_t)255;
        return p;
    };
    u16* Mhb  = (u16*)alloc(sizeof(u16) * F * E);
    float* wvec = (float*)alloc(sizeof(float) * F);
    float* cvec = (float*)alloc(sizeof(float) * E);
    u16* Ntb  = (u16*)alloc(sizeof(u16) * E * F);
    _Float16* q16 = (_Float16*)alloc(sizeof(u16) * (size_t)BB * LQ * F);
    _Float16* yA  = (_Float16*)alloc(sizeof(u16) * (size_t)BB * LK * F);
    _Float16* yB  = (_Float16*)alloc(sizeof(u16) * (size_t)BB * LK * F);
    _Float16* part = (_Float16*)alloc(sizeof(u16) * 4 * (size_t)BB * LQ * F);
    float* ml = (float*)alloc(sizeof(float) * 2 * 4 * (size_t)BB * LQ);
    (void)ws_size; (void)in_sizes; (void)n_in; (void)out_size;

    prew<<<dim3(1091), dim3(256), 0, stream>>>(
        y, yA, yB, Wq, bq, Wk, Wv, bv, Wo, bo, Mhb, Ntb, wvec, cvec);
    qprime5<<<dim3(BB * LQ / 64, 2), dim3(256), 0, stream>>>(x, Mhb, wvec, q16);
    flash6<<<dim3(256), dim3(512), 0, stream>>>(q16, yA, yB, part, ml);
    gemm2c<<<dim3(BB * LQ / 64, E / 256), dim3(256), 0, stream>>>(
        part, ml, Ntb, cvec, out);
}